// Round 15
// baseline (307.663 us; speedup 1.0000x reference)
//
#include <hip/hip_runtime.h>
#include <math.h>

#define BATCH 8
#define SEQ 1024
#define D_MODEL 512
#define D_INNER 1024
#define D_STATE 16
#define DT_RANK 32
#define NROWS (BATCH * SEQ)   // 8192
#define CH 64                 // chunks per sequence
#define CL 16                 // chunk length
#define USLAB 8388608l        // 8192*1024 elems (one dir slab)

typedef short short8 __attribute__((ext_vector_type(8)));
typedef float f32x4 __attribute__((ext_vector_type(4)));

__device__ __forceinline__ float sigmoidf_(float x) { return 1.f / (1.f + __expf(-x)); }

__device__ __forceinline__ float softplus_(float v) {
  return (v > 20.f) ? v : __logf(1.f + __expf(v));
}

__device__ __forceinline__ ushort f2b(float f) {  // fp32 -> bf16 RNE
  uint u = __float_as_uint(f);
  return (ushort)((u + 0x7FFFu + ((u >> 16) & 1u)) >> 16);
}
__device__ __forceinline__ float b2f(ushort u) {
  return __uint_as_float(((uint)u) << 16);
}

__device__ __forceinline__ void gload16(const ushort* g, const ushort* l) {
  __builtin_amdgcn_global_load_lds(
      (const __attribute__((address_space(1))) void*)g,
      (__attribute__((address_space(3))) void*)l, 16, 0, 0);
}

__device__ __forceinline__ int revrow(int m) {
  return (m & ~1023) | (1023 - (m & 1023));
}

// ========== in_proj: 256x256 tile, 8 waves, counted-vmcnt pipeline =========
__global__ __launch_bounds__(512, 2) void inproj256(
    const ushort* __restrict__ A, int lda,      // [8192][512]
    const ushort* __restrict__ B, int ldb,      // [4096][512]
    ushort* __restrict__ Cu, ushort* __restrict__ Cz,
    int K)
{
  __shared__ ushort As[3][256 * 32];
  __shared__ ushort Bs[3][256 * 32];
  const int tid = threadIdx.x;
  const int w = tid >> 6, lane = tid & 63;

  const int nwg = gridDim.x * gridDim.y;        // %8 == 0
  int bid = blockIdx.y * gridDim.x + blockIdx.x;
  int wgid = (bid & 7) * (nwg >> 3) + (bid >> 3);
  const int bm = (wgid / gridDim.x) * 256;
  const int bn = (wgid % gridDim.x) * 256;

  const int wr = w >> 2, wc = w & 3;
  const int rw0 = wr * 128, cw0 = wc * 64;
  const int srow = w * 16 + (lane >> 2);
  const int scol = (((lane & 3) ^ ((lane >> 3) & 3)) << 3);
  const int rchunk = (((lane >> 4) ^ (((lane & 15) >> 1) & 3)) << 3);

  f32x4 acc[8][4] = {};

  auto stageA = [&](int buf, int k0, int half) {
    int gm = bm + half * 128 + srow;
    gload16(A + (long)gm * lda + k0 + scol, &As[buf][(half * 128 + w * 16) * 32]);
  };
  auto stageB = [&](int buf, int k0, int half) {
    int gn = bn + half * 128 + srow;
    gload16(B + (long)gn * ldb + k0 + scol, &Bs[buf][(half * 128 + w * 16) * 32]);
  };

  const int NT = K >> 5;
  stageA(0, 0, 0); stageA(0, 0, 1); stageB(0, 0, 0); stageB(0, 0, 1);
  stageA(1, 32, 0); stageA(1, 32, 1); stageB(1, 32, 0); stageB(1, 32, 1);
  asm volatile("s_waitcnt vmcnt(4)" ::: "memory");
  __builtin_amdgcn_s_barrier();

  int buf = 0;
  for (int t = 0; t < NT; ++t) {
    const int kf = (t + 2) << 5;
    const int sbuf = (buf >= 1) ? buf - 1 : buf + 2;
    short8 a0[4], b0[4];
#pragma unroll
    for (int i = 0; i < 4; ++i)
      a0[i] = *(const short8*)&As[buf][(rw0 + i * 16 + (lane & 15)) * 32 + rchunk];
#pragma unroll
    for (int j = 0; j < 4; ++j)
      b0[j] = *(const short8*)&Bs[buf][(cw0 + j * 16 + (lane & 15)) * 32 + rchunk];
    if (t + 2 < NT) { stageA(sbuf, kf, 0); stageA(sbuf, kf, 1); }
    __builtin_amdgcn_s_barrier();
    __builtin_amdgcn_s_setprio(1);
#pragma unroll
    for (int i = 0; i < 4; ++i)
#pragma unroll
      for (int j = 0; j < 4; ++j)
        acc[i][j] = __builtin_amdgcn_mfma_f32_16x16x32_bf16(a0[i], b0[j], acc[i][j], 0, 0, 0);
    __builtin_amdgcn_s_setprio(0);
    __builtin_amdgcn_s_barrier();
    short8 a1[4];
#pragma unroll
    for (int i = 0; i < 4; ++i)
      a1[i] = *(const short8*)&As[buf][(rw0 + 64 + i * 16 + (lane & 15)) * 32 + rchunk];
    if (t + 2 < NT) {
      stageB(sbuf, kf, 0); stageB(sbuf, kf, 1);
      asm volatile("s_waitcnt vmcnt(4)" ::: "memory");
    } else if (t + 1 < NT) {
      asm volatile("s_waitcnt vmcnt(0)" ::: "memory");
    }
    __builtin_amdgcn_s_barrier();
    __builtin_amdgcn_s_setprio(1);
#pragma unroll
    for (int i = 0; i < 4; ++i)
#pragma unroll
      for (int j = 0; j < 4; ++j)
        acc[4 + i][j] = __builtin_amdgcn_mfma_f32_16x16x32_bf16(a1[i], b0[j], acc[4 + i][j], 0, 0, 0);
    __builtin_amdgcn_s_setprio(0);
    __builtin_amdgcn_s_barrier();
    buf = (buf == 2) ? 0 : buf + 1;
  }

  const int bdir = bn >> 11;
  const int bz = ((bn & 2047) >= 1024);
  const int bncol = bn & 1023;
  ushort* Cp = (bz ? Cz : Cu) + (long)bdir * USLAB;
  ushort* scr = &As[0][0] + w * 1024;

#pragma unroll
  for (int i = 0; i < 8; ++i) {
#pragma unroll
    for (int r = 0; r < 4; ++r)
#pragma unroll
      for (int j = 0; j < 4; ++j) {
        float v = acc[i][j][r];
        if (bz) v = v * sigmoidf_(v);
        scr[((lane >> 4) * 4 + r) * 64 + j * 16 + (lane & 15)] = f2b(v);
      }
#pragma unroll
    for (int q = 0; q < 2; ++q) {
      int r16 = (lane >> 3) + q * 8;
      short8 pk = *(const short8*)&scr[r16 * 64 + (lane & 7) * 8];
      int m = bm + rw0 + i * 16 + r16;
      int row = bdir ? revrow(m) : m;
      *(short8*)&Cp[(long)row * 1024 + bncol + cw0 + (lane & 7) * 8] = pk;
    }
  }
}

// ========== x_proj with fused conv+silu A-staging ==========
// A-tile rows = token rows; conv(u) computed in regs (global->reg->conv->
// ds_write with write-side XOR matching the gload layout, rule #21).
__global__ __launch_bounds__(256) void xproj_conv(
    const ushort* __restrict__ u,        // [16384][1024] (both dirs)
    const ushort* __restrict__ xp_w,     // [2][64][1024]
    const float* __restrict__ cw_f, const float* __restrict__ cw_b,
    const float* __restrict__ cb_f, const float* __restrict__ cb_b,
    ushort* __restrict__ dblb)           // [16384][64]
{
  __shared__ ushort As[2][64 * 32];
  __shared__ ushort Bs[2][64 * 32];
  const int tid = threadIdx.x;
  const int w = tid >> 6, lane = tid & 63;
  const int nwg = gridDim.x;             // 256
  int wgid = (blockIdx.x & 7) * (nwg >> 3) + (blockIdx.x >> 3);
  const int bm = wgid * 64;
  const int mdir = (bm >= NROWS) ? 1 : 0;
  const ushort* B = xp_w + mdir * 65536;
  const float* cw = mdir ? cw_b : cw_f;
  const float* cb = mdir ? cb_b : cb_f;

  const int rw0 = (w >> 1) * 32;
  const int cw0 = (w & 1) * 32;
  const int srow = w * 16 + (lane >> 2);
  const int scol = (((lane & 3) ^ ((lane >> 3) & 3)) << 3);
  const int rchunk = (((lane >> 4) ^ (((lane & 15) >> 1) & 3)) << 3);

  const int ri = tid >> 2, cg = tid & 3;   // A-staging: row, 8-col group
  const int gr = bm + ri;
  const int tt = gr & (SEQ - 1);
  const int wchunk = (cg ^ ((ri >> 1) & 3)) * 8;  // swizzled LDS chunk pos

  f32x4 acc[2][2] = {};
  short8 z8 = {0, 0, 0, 0, 0, 0, 0, 0};
  short8 ur0 = z8, ur1 = z8, ur2 = z8, ur3 = z8;

  auto issueA = [&](int k0) {
    const ushort* p = u + (long)gr * 1024 + k0 + cg * 8;
    ur0 = *(const short8*)p;
    ur1 = (tt >= 1) ? *(const short8*)(p - 1024) : z8;
    ur2 = (tt >= 2) ? *(const short8*)(p - 2048) : z8;
    ur3 = (tt >= 3) ? *(const short8*)(p - 3072) : z8;
  };
  auto convWrite = [&](int buf, int k0) {
    int dc = k0 + cg * 8;
    short8 o;
#pragma unroll
    for (int j = 0; j < 8; ++j) {
      float4 wj = *(const float4*)(cw + (dc + j) * 4);
      float a = cb[dc + j];
      a = fmaf(wj.w, b2f((ushort)ur0[j]), a);
      a = fmaf(wj.z, b2f((ushort)ur1[j]), a);
      a = fmaf(wj.y, b2f((ushort)ur2[j]), a);
      a = fmaf(wj.x, b2f((ushort)ur3[j]), a);
      o[j] = (short)f2b(a * sigmoidf_(a));
    }
    *(short8*)&As[buf][ri * 32 + wchunk] = o;
  };
  auto stageB = [&](int buf, int k0) {
    gload16(B + (long)srow * 1024 + k0 + scol, &Bs[buf][(w * 16) * 32]);
  };

  issueA(0);
  stageB(0, 0);
  convWrite(0, 0);
  __syncthreads();

  for (int k0 = 0; k0 < 1024; k0 += 32) {
    int cur = (k0 >> 5) & 1;
    bool more = (k0 + 32 < 1024);
    if (more) { issueA(k0 + 32); stageB(cur ^ 1, k0 + 32); }
    short8 a[2], b[2];
#pragma unroll
    for (int i = 0; i < 2; ++i)
      a[i] = *(const short8*)&As[cur][(rw0 + i * 16 + (lane & 15)) * 32 + rchunk];
#pragma unroll
    for (int j = 0; j < 2; ++j)
      b[j] = *(const short8*)&Bs[cur][(cw0 + j * 16 + (lane & 15)) * 32 + rchunk];
#pragma unroll
    for (int i = 0; i < 2; ++i)
#pragma unroll
      for (int j = 0; j < 2; ++j)
        acc[i][j] = __builtin_amdgcn_mfma_f32_16x16x32_bf16(a[i], b[j], acc[i][j], 0, 0, 0);
    if (more) convWrite(cur ^ 1, k0 + 32);
    __syncthreads();
  }

#pragma unroll
  for (int i = 0; i < 2; ++i)
#pragma unroll
    for (int r = 0; r < 4; ++r) {
      int m = bm + rw0 + i * 16 + (lane >> 4) * 4 + r;
#pragma unroll
      for (int j = 0; j < 2; ++j) {
        int n = cw0 + j * 16 + (lane & 15);
        dblb[(long)m * 64 + n] = f2b(acc[i][j][r]);
      }
    }
}

// ---------------- bf16 MFMA GEMM: 2-phase dbuf + T2 swizzle + T1 -----------
// EPI: 0 = fp32 store (revC/accumC), 1 = softplus->bf16 (LDS-transposed)
template<int BM, int BN, int RW, int CW, int EPI, int DUALK, int MDIAG>
__global__ __launch_bounds__(256) void gemm_bf16(
    const ushort* __restrict__ A, int lda, const ushort* __restrict__ A2,
    const ushort* __restrict__ B, int ldb, const ushort* __restrict__ B2,
    float* __restrict__ Cf, ushort* __restrict__ Cb,
    int ldc, int K, const float* __restrict__ bias, const float* __restrict__ bias2,
    int b_stride, int revC, int accumC)
{
  constexpr int MI = BM / RW / 16;
  constexpr int NJ = BN / CW / 16;
  __shared__ ushort As[2][BM * 32];
  __shared__ ushort Bs[2][BN * 32];
  const int tid = threadIdx.x;
  const int w = tid >> 6, lane = tid & 63;

  const int nwg = gridDim.x * gridDim.y;
  int bid = blockIdx.y * gridDim.x + blockIdx.x;
  int wgid = (bid & 7) * (nwg >> 3) + (bid >> 3);
  const int bm = (wgid / gridDim.x) * BM;
  const int bn = (wgid % gridDim.x) * BN;

  if (MDIAG) {
    int mdir = (bm >= NROWS) ? 1 : 0;
    B += mdir * b_stride;
    if (mdir) bias = bias2;
  }

  const int rw0 = (w / CW) * (MI * 16);
  const int cw0 = (w % CW) * (NJ * 16);
  const int srow = w * 16 + (lane >> 2);
  const int scol = (((lane & 3) ^ ((lane >> 3) & 3)) << 3);
  const int rchunk = (((lane >> 4) ^ (((lane & 15) >> 1) & 3)) << 3);

  f32x4 acc[MI][NJ] = {};

  auto stage = [&](int buf, int k0) {
    const ushort* Ap = A;
    const ushort* Bp = B;
    int kc = k0;
    bool hi = false;
    if (DUALK && k0 >= (K >> 1)) { Ap = A2; Bp = B2; kc = k0 - (K >> 1); hi = true; }
#pragma unroll
    for (int it = 0; it < BM / 64; ++it) {
      int gm = bm + it * 64 + srow;
      int arow = (DUALK && hi) ? revrow(gm) : gm;
      gload16(Ap + (long)arow * lda + kc + scol, &As[buf][(it * 64 + w * 16) * 32]);
    }
#pragma unroll
    for (int it = 0; it < BN / 64; ++it) {
      int gn = bn + it * 64 + srow;
      gload16(Bp + (long)gn * ldb + kc + scol, &Bs[buf][(it * 64 + w * 16) * 32]);
    }
  };

  stage(0, 0);
  __syncthreads();

  for (int k0 = 0; k0 < K; k0 += 32) {
    int cur = (k0 >> 5) & 1;
    if (k0 + 32 < K) stage(cur ^ 1, k0 + 32);
    short8 a[MI], b[NJ];
#pragma unroll
    for (int i = 0; i < MI; ++i)
      a[i] = *(const short8*)&As[cur][(rw0 + i * 16 + (lane & 15)) * 32 + rchunk];
#pragma unroll
    for (int j = 0; j < NJ; ++j)
      b[j] = *(const short8*)&Bs[cur][(cw0 + j * 16 + (lane & 15)) * 32 + rchunk];
#pragma unroll
    for (int i = 0; i < MI; ++i)
#pragma unroll
      for (int j = 0; j < NJ; ++j)
        acc[i][j] = __builtin_amdgcn_mfma_f32_16x16x32_bf16(a[i], b[j], acc[i][j], 0, 0, 0);
    __syncthreads();
  }

  if (EPI == 1) {
    ushort* scr = &As[0][0] + w * 1024;
#pragma unroll
    for (int i = 0; i < MI; ++i) {
#pragma unroll
      for (int r = 0; r < 4; ++r)
#pragma unroll
        for (int j = 0; j < NJ; ++j) {
          int n = bn + cw0 + j * 16 + (lane & 15);
          float v = softplus_(acc[i][j][r] + bias[n]);
          scr[((lane >> 4) * 4 + r) * 64 + j * 16 + (lane & 15)] = f2b(v);
        }
#pragma unroll
      for (int q = 0; q < 2; ++q) {
        int r16 = (lane >> 3) + q * 8;
        short8 pk = *(const short8*)&scr[r16 * 64 + (lane & 7) * 8];
        int m = bm + rw0 + i * 16 + r16;
        *(short8*)&Cb[(long)m * ldc + bn + cw0 + (lane & 7) * 8] = pk;
      }
    }
  } else {
#pragma unroll
    for (int i = 0; i < MI; ++i)
#pragma unroll
      for (int r = 0; r < 4; ++r) {
        int m = bm + rw0 + i * 16 + (lane >> 4) * 4 + r;
        int crow = revC ? revrow(m) : m;
#pragma unroll
        for (int j = 0; j < NJ; ++j) {
          int n = bn + cw0 + j * 16 + (lane & 15);
          float v = acc[i][j][r];
          float* p = Cf + (long)crow * ldc + n;
          if (accumC) *p += v; else *p = v;
        }
      }
  }
}

// ---------------- fused fp32->bf16 converter (x + 8 weight tensors) --------
struct Seg { const float4* s; ushort4* d; int n4; int bstart; };
struct ConvArgs { Seg seg[9]; };

__global__ __launch_bounds__(256) void convert_all(ConvArgs a)
{
  int blk = blockIdx.x;
  int i = 0;
#pragma unroll
  for (int k = 1; k < 9; ++k) if (blk >= a.seg[k].bstart) i = k;
  int idx = (blk - a.seg[i].bstart) * 256 + threadIdx.x;
  if (idx >= a.seg[i].n4) return;
  float4 v = a.seg[i].s[idx];
  ushort4 o;
  o.x = f2b(v.x); o.y = f2b(v.y); o.z = f2b(v.z); o.w = f2b(v.w);
  a.seg[i].d[idx] = o;
}

// Decay powers E^(s+1), s=0..15, from E = exp(-dt).
#define EP_FAST(dt, Ep)                                        \
  {                                                            \
    float E1 = __expf(-(dt));                                  \
    float E2 = E1 * E1, E4 = E2 * E2, E8 = E4 * E4;            \
    Ep[0] = E1;  Ep[1] = E2;      Ep[2] = E2 * E1;             \
    Ep[3] = E4;  Ep[4] = E4 * E1; Ep[5] = E4 * E2;             \
    Ep[6] = E4 * Ep[2]; Ep[7] = E8;  Ep[8] = E8 * E1;          \
    Ep[9] = E8 * E2; Ep[10] = E8 * Ep[2]; Ep[11] = E8 * E4;    \
    Ep[12] = E8 * Ep[4]; Ep[13] = E8 * Ep[5];                  \
    Ep[14] = E8 * Ep[6]; Ep[15] = E8 * E8;                     \
  }

__device__ __forceinline__ bool a_is_arange(const float* Ar) {
  bool ok = true;
#pragma unroll
  for (int s = 0; s < D_STATE; ++s)
    ok = ok && (fabsf(Ar[s] + (float)(s + 1)) <= 1e-3f * (float)(s + 1));
  return ok;
}

// ---------------- chunked selective scan with fused conv -------------------
// idx bits: d[0:10) c[10:16) b[16:19) dir[19]
__global__ __launch_bounds__(256) void scan_partA(
    const ushort* __restrict__ delta_bf,  // [2][8192][1024]
    const ushort* __restrict__ u_bf,      // [2][8192][1024] (pre-conv u)
    const ushort* __restrict__ dblb,
    const float* __restrict__ A_log_f, const float* __restrict__ A_log_b,
    const float* __restrict__ cw_f, const float* __restrict__ cw_b,
    const float* __restrict__ cb_f, const float* __restrict__ cb_b,
    ushort* __restrict__ hend,
    float* __restrict__ dtsum_buf,
    ushort* __restrict__ prim)            // [2*8*CH][3][1024] conv primers
{
  __shared__ float bc[CL][16];
  long idx = (long)blockIdx.x * 256 + threadIdx.x;
  int d = (int)idx & 1023;
  int c = ((int)idx >> 10) & (CH - 1);
  int b = ((int)idx >> 16) & 7;
  int dir = (int)(idx >> 19);
  const long r0 = (long)b * SEQ + c * CL;
  const ushort* dblp = dblb + (long)dir * NROWS * 64;
  {
    int tt = threadIdx.x >> 4, ss = threadIdx.x & 15;
    bc[tt][ss] = b2f(dblp[(r0 + tt) * 64 + 32 + ss]);
  }
  const float* Alog = dir ? A_log_b : A_log_f;
  const ushort* dp = delta_bf + dir * USLAB;
  const ushort* up = u_bf + dir * USLAB;
  const float4 wj = *(const float4*)((dir ? cw_b : cw_f) + d * 4);
  const float cbd = (dir ? cb_b : cb_f)[d];
  float Ar[D_STATE];
#pragma unroll
  for (int s = 0; s < D_STATE; ++s) Ar[s] = -__expf(Alog[d * D_STATE + s]);
  const bool fast = a_is_arange(Ar);
  float h[D_STATE] = {0.f};
  float dtsum = 0.f;
  // conv priming (t0 = c*CL; for c>0 all exist)
  int t0 = c * CL;
  float um1 = 0.f, um2 = 0.f, um3 = 0.f;
  if (t0 >= 1) um1 = b2f(up[(r0 - 1) * 1024 + d]);
  if (t0 >= 2) um2 = b2f(up[(r0 - 2) * 1024 + d]);
  if (t0 >= 3) um3 = b2f(up[(r0 - 3) * 1024 + d]);
  // stash primers for scan_partC (which overwrites u in-place)
  long gix = (long)((dir * 8 + b) * CH + c) * 3;
  prim[(gix + 0) * 1024 + d] = f2b(um1);
  prim[(gix + 1) * 1024 + d] = f2b(um2);
  prim[(gix + 2) * 1024 + d] = f2b(um3);
  __syncthreads();

  for (int t = 0; t < CL; ++t) {
    long r = r0 + t;
    float dt = b2f(dp[r * 1024 + d]);
    float ucur = b2f(up[r * 1024 + d]);
    float ca = cbd;
    ca = fmaf(wj.w, ucur, ca);
    ca = fmaf(wj.z, um1, ca);
    ca = fmaf(wj.y, um2, ca);
    ca = fmaf(wj.x, um3, ca);
    float uc = ca * sigmoidf_(ca);
    um3 = um2; um2 = um1; um1 = ucur;
    float du = dt * uc;
    dtsum += dt;
    if (fast) {
      float Ep[16];
      EP_FAST(dt, Ep);
#pragma unroll
      for (int s = 0; s < D_STATE; ++s)
        h[s] = fmaf(h[s], Ep[s], du * bc[t][s]);
    } else {
#pragma unroll
      for (int s = 0; s < D_STATE; ++s)
        h[s] = fmaf(h[s], __expf(dt * Ar[s]), du * bc[t][s]);
    }
  }
  long base = ((long)((dir * 8 + b) * CH + c) * D_STATE) * 1024 + d;
#pragma unroll
  for (int s = 0; s < D_STATE; ++s) hend[base + s * 1024] = f2b(h[s]);
  dtsum_buf[(long)((dir * 8 + b) * CH + c) * 1024 + d] = dtsum;
}

// idx bits: d[0:10) s[10:14) b[14:17) dir[17]
__global__ __launch_bounds__(256) void scan_partB(
    ushort* __restrict__ hend,
    const float* __restrict__ dtsum_buf,
    const float* __restrict__ A_log_f, const float* __restrict__ A_log_b)
{
  long idx = (long)blockIdx.x * 256 + threadIdx.x;
  int d = (int)idx & 1023;
  int s = ((int)idx >> 10) & 15;
  int b = ((int)idx >> 14) & 7;
  int dir = (int)(idx >> 17);
  const float* Alog = dir ? A_log_b : A_log_f;
  float Ars = -__expf(Alog[d * D_STATE + s]);
  float H = 0.f;
  for (int c = 0; c < CH; ++c) {
    long off = ((long)((dir * 8 + b) * CH + c) * D_STATE + s) * 1024 + d;
    float he = b2f(hend[off]);
    float P = __expf(Ars * dtsum_buf[(long)((dir * 8 + b) * CH + c) * 1024 + d]);
    hend[off] = f2b(H);
    H = fmaf(P, H, he);
  }
}

__global__ __launch_bounds__(256) void scan_partC(
    const ushort* __restrict__ delta_bf,
    const ushort* u_bf,                   // aliases ydz (in-place, no restrict)
    const ushort* __restrict__ dblb,
    const float* __restrict__ A_log_f, const float* __restrict__ A_log_b,
    const float* __restrict__ Dp_f, const float* __restrict__ Dp_b,
    const float* __restrict__ cw_f, const float* __restrict__ cw_b,
    const float* __restrict__ cb_f, const float* __restrict__ cb_b,
    const ushort* __restrict__ zsilu_bf,
    const ushort* __restrict__ hinit,
    const ushort* __restrict__ prim,
    ushort* ydz_bf)                       // = u_bf slab
{
  __shared__ float bc[CL][32];
  long idx = (long)blockIdx.x * 256 + threadIdx.x;
  int d = (int)idx & 1023;
  int c = ((int)idx >> 10) & (CH - 1);
  int b = ((int)idx >> 16) & 7;
  int dir = (int)(idx >> 19);
  const long r0 = (long)b * SEQ + c * CL;
  const ushort* dblp = dblb + (long)dir * NROWS * 64;
  {
    int tt = threadIdx.x >> 4, cc = (threadIdx.x & 15) * 2;
    ushort2 v = *(const ushort2*)&dblp[(r0 + tt) * 64 + 32 + cc];
    bc[tt][cc] = b2f(v.x); bc[tt][cc + 1] = b2f(v.y);
  }
  const float* Alog = dir ? A_log_b : A_log_f;
  const ushort* dp = delta_bf + dir * USLAB;
  const ushort* up = u_bf + dir * USLAB;
  const ushort* zp = zsilu_bf + dir * USLAB;
  ushort* yp = ydz_bf + dir * USLAB;
  const float4 wj = *(const float4*)((dir ? cw_b : cw_f) + d * 4);
  const float cbd = (dir ? cb_b : cb_f)[d];
  float Ar[D_STATE];
#pragma unroll
  for (int s = 0; s < D_STATE; ++s) Ar[s] = -__expf(Alog[d * D_STATE + s]);
  const bool fast = a_is_arange(Ar);
  float h[D_STATE];
  long base = ((long)((dir * 8 + b) * CH + c) * D_STATE) * 1024 + d;
#pragma unroll
  for (int s = 0; s < D_STATE; ++s) h[s] = b2f(hinit[base + s * 1024]);
  float Dd = (dir ? Dp_b : Dp_f)[d];
  // conv primers from scanA's stash (u rows of chunk c-1 may be overwritten)
  long gix = (long)((dir * 8 + b) * CH + c) * 3;
  float um1 = b2f(prim[(gix + 0) * 1024 + d]);
  float um2 = b2f(prim[(gix + 1) * 1024 + d]);
  float um3 = b2f(prim[(gix + 2) * 1024 + d]);
  __syncthreads();

  for (int t = 0; t < CL; ++t) {
    long r = r0 + t;
    float dt = b2f(dp[r * 1024 + d]);
    float ucur = b2f(up[r * 1024 + d]);
    float ca = cbd;
    ca = fmaf(wj.w, ucur, ca);
    ca = fmaf(wj.z, um1, ca);
    ca = fmaf(wj.y, um2, ca);
    ca = fmaf(wj.x, um3, ca);
    float uc = ca * sigmoidf_(ca);
    um3 = um2; um2 = um1; um1 = ucur;
    float du = dt * uc;
    float y = 0.f;
    if (fast) {
      float Ep[16];
      EP_FAST(dt, Ep);
#pragma unroll
      for (int s = 0; s < D_STATE; ++s) {
        h[s] = fmaf(h[s], Ep[s], du * bc[t][s]);
        y = fmaf(h[s], bc[t][16 + s], y);
      }
    } else {
#pragma unroll
      for (int s = 0; s < D_STATE; ++s) {
        h[s] = fmaf(h[s], __expf(dt * Ar[s]), du * bc[t][s]);
        y = fmaf(h[s], bc[t][16 + s], y);
      }
    }
    float zs = b2f(zp[r * 1024 + d]);
    float yv = fmaf(uc, Dd, y);
    yp[r * 1024 + d] = f2b(yv * zs);
  }
}

extern "C" void kernel_launch(void* const* d_in, const int* in_sizes, int n_in,
                              void* d_out, int out_size, void* d_ws, size_t ws_size,
                              hipStream_t stream)
{
  const float* x = (const float*)d_in[0];
  float* out = (float*)d_out;
  char* ws = (char*)d_ws;
  ushort* zsilu  = (ushort*)(ws);                     // 32 MiB
  ushort* u_bf   = (ushort*)(ws + (32ul << 20));      // 32 MiB (ydz in-place)
  ushort* delta  = (ushort*)(ws + (64ul << 20));      // 32 MiB
  ushort* hend   = (ushort*)(ws + (96ul << 20));      // 32 MiB
  float*  dtsum  = (float*)(ws + (128ul << 20));      //  4 MiB
  ushort* dblb   = (ushort*)(ws + (132ul << 20));     //  2 MiB
  ushort* out_wb = (ushort*)(ws + (134ul << 20));     //  2 MiB
  ushort* prim   = (ushort*)(ws + (136ul << 20));     //  6 MiB
  ushort* xbf    = hend;                              // transient in hend slab
  ushort* in_wb  = hend + (8ul << 19);
  ushort* xp_wb  = hend + (12ul << 19);
  ushort* dt_wb  = xp_wb + 131072;
  ushort* ydz    = u_bf;

  ConvArgs ca;
  int bcur = 0, si = 0;
  auto addseg = [&](const float* s, ushort* d, int nelem) {
    ca.seg[si].s = (const float4*)s; ca.seg[si].d = (ushort4*)d;
    ca.seg[si].n4 = nelem / 4; ca.seg[si].bstart = bcur;
    bcur += (nelem / 4 + 255) / 256; ++si;
  };
  addseg(x, xbf, NROWS * D_MODEL);
  addseg((const float*)d_in[1], in_wb, 2048 * 512);
  addseg((const float*)d_in[10], in_wb + 2048 * 512, 2048 * 512);
  addseg((const float*)d_in[9], out_wb, 512 * 1024);
  addseg((const float*)d_in[18], out_wb + 512 * 1024, 512 * 1024);
  addseg((const float*)d_in[4], xp_wb, 64 * 1024);
  addseg((const float*)d_in[13], xp_wb + 65536, 64 * 1024);
  addseg((const float*)d_in[5], dt_wb, 1024 * 32);
  addseg((const float*)d_in[14], dt_wb + 32768, 1024 * 32);

  dim3 blk(256);
  convert_all<<<dim3(bcur), blk, 0, stream>>>(ca);

  const float* cwf = (const float*)d_in[2];
  const float* cwb = (const float*)d_in[11];
  const float* cbf = (const float*)d_in[3];
  const float* cbb = (const float*)d_in[12];
  const float* Alf = (const float*)d_in[7];
  const float* Alb = (const float*)d_in[16];

  // 1) merged in_proj -> u (pre-conv) + zsilu
  inproj256<<<dim3(4096 / 256, NROWS / 256), dim3(512), 0, stream>>>(
      xbf, D_MODEL, in_wb, D_MODEL, u_bf, zsilu, D_MODEL);
  // 2) x_proj with fused conv+silu A-staging -> dblb
  xproj_conv<<<dim3(256), blk, 0, stream>>>(
      u_bf, xp_wb, cwf, cwb, cbf, cbb, dblb);
  // 3) dt_proj + softplus, both dirs block-diag (LDS-vectorized epilogue)
  gemm_bf16<128, 128, 2, 2, 1, 0, 1><<<dim3(8, 128), blk, 0, stream>>>(
      dblb, 64, nullptr, dt_wb, DT_RANK, nullptr,
      nullptr, delta, D_INNER, DT_RANK,
      (const float*)d_in[6], (const float*)d_in[15], 32768, 0, 0);
  // 4) chunked scan with fused conv, both dirs
  scan_partA<<<dim3(2 * BATCH * CH * 1024 / 256), blk, 0, stream>>>(
      delta, u_bf, dblb, Alf, Alb, cwf, cwb, cbf, cbb, hend, dtsum, prim);
  scan_partB<<<dim3(2 * BATCH * 16 * 1024 / 256), blk, 0, stream>>>(
      hend, dtsum, Alf, Alb);
  scan_partC<<<dim3(2 * BATCH * CH * 1024 / 256), blk, 0, stream>>>(
      delta, u_bf, dblb, Alf, Alb,
      (const float*)d_in[8], (const float*)d_in[17],
      cwf, cwb, cbf, cbb, zsilu, hend, prim, ydz);
  // 5) out_proj, both dirs in one K=2048 dispatch
  gemm_bf16<128, 128, 2, 2, 0, 1, 0><<<dim3(4, 64), blk, 0, stream>>>(
      ydz, D_INNER, ydz + USLAB, out_wb, D_INNER, out_wb + 512 * 1024,
      out, nullptr, D_MODEL, 2 * D_INNER, nullptr, nullptr, 0, 0, 0);
}

// Round 16
// 257.177 us; speedup vs baseline: 1.1963x; 1.1963x over previous
//
#include <hip/hip_runtime.h>
#include <math.h>

#define BATCH 8
#define SEQ 1024
#define D_MODEL 512
#define D_INNER 1024
#define D_STATE 16
#define DT_RANK 32
#define NROWS (BATCH * SEQ)   // 8192
#define CH 64                 // chunks per sequence
#define CL 16                 // chunk length
#define USLAB 8388608l        // 8192*1024 elems (one dir slab)

typedef short short8 __attribute__((ext_vector_type(8)));
typedef float f32x4 __attribute__((ext_vector_type(4)));

__device__ __forceinline__ float sigmoidf_(float x) { return 1.f / (1.f + __expf(-x)); }

__device__ __forceinline__ float softplus_(float v) {
  return (v > 20.f) ? v : __logf(1.f + __expf(v));
}

__device__ __forceinline__ ushort f2b(float f) {  // fp32 -> bf16 RNE
  uint u = __float_as_uint(f);
  return (ushort)((u + 0x7FFFu + ((u >> 16) & 1u)) >> 16);
}
__device__ __forceinline__ float b2f(ushort u) {
  return __uint_as_float(((uint)u) << 16);
}

__device__ __forceinline__ void gload16(const ushort* g, const ushort* l) {
  __builtin_amdgcn_global_load_lds(
      (const __attribute__((address_space(1))) void*)g,
      (__attribute__((address_space(3))) void*)l, 16, 0, 0);
}

__device__ __forceinline__ int revrow(int m) {
  return (m & ~1023) | (1023 - (m & 1023));
}

// ========== in_proj: 256x256 tile, 8 waves, counted-vmcnt pipeline =========
// Epilogue: per-wave LDS transpose -> full-line dwordx4 stores.
__global__ __launch_bounds__(512, 2) void inproj256(
    const ushort* __restrict__ A, int lda,      // [8192][512]
    const ushort* __restrict__ B, int ldb,      // [4096][512]
    ushort* __restrict__ Cu, ushort* __restrict__ Cz,
    int K)
{
  __shared__ ushort As[3][256 * 32];
  __shared__ ushort Bs[3][256 * 32];
  const int tid = threadIdx.x;
  const int w = tid >> 6, lane = tid & 63;

  const int nwg = gridDim.x * gridDim.y;        // %8 == 0
  int bid = blockIdx.y * gridDim.x + blockIdx.x;
  int wgid = (bid & 7) * (nwg >> 3) + (bid >> 3);
  const int bm = (wgid / gridDim.x) * 256;
  const int bn = (wgid % gridDim.x) * 256;

  const int wr = w >> 2, wc = w & 3;            // 2x4 wave grid
  const int rw0 = wr * 128, cw0 = wc * 64;      // per-wave 128x64 output
  const int srow = w * 16 + (lane >> 2);
  const int scol = (((lane & 3) ^ ((lane >> 3) & 3)) << 3);
  const int rchunk = (((lane >> 4) ^ (((lane & 15) >> 1) & 3)) << 3);

  f32x4 acc[8][4] = {};

  auto stageA = [&](int buf, int k0, int half) {
    int gm = bm + half * 128 + srow;
    gload16(A + (long)gm * lda + k0 + scol, &As[buf][(half * 128 + w * 16) * 32]);
  };
  auto stageB = [&](int buf, int k0, int half) {
    int gn = bn + half * 128 + srow;
    gload16(B + (long)gn * ldb + k0 + scol, &Bs[buf][(half * 128 + w * 16) * 32]);
  };

  const int NT = K >> 5;                         // 16 for K=512
  stageA(0, 0, 0); stageA(0, 0, 1); stageB(0, 0, 0); stageB(0, 0, 1);
  stageA(1, 32, 0); stageA(1, 32, 1); stageB(1, 32, 0); stageB(1, 32, 1);
  asm volatile("s_waitcnt vmcnt(4)" ::: "memory");
  __builtin_amdgcn_s_barrier();

  int buf = 0;
  for (int t = 0; t < NT; ++t) {
    const int kf = (t + 2) << 5;
    const int sbuf = (buf >= 1) ? buf - 1 : buf + 2;
    short8 a0[4], b0[4];
#pragma unroll
    for (int i = 0; i < 4; ++i)
      a0[i] = *(const short8*)&As[buf][(rw0 + i * 16 + (lane & 15)) * 32 + rchunk];
#pragma unroll
    for (int j = 0; j < 4; ++j)
      b0[j] = *(const short8*)&Bs[buf][(cw0 + j * 16 + (lane & 15)) * 32 + rchunk];
    if (t + 2 < NT) { stageA(sbuf, kf, 0); stageA(sbuf, kf, 1); }
    __builtin_amdgcn_s_barrier();
    __builtin_amdgcn_s_setprio(1);
#pragma unroll
    for (int i = 0; i < 4; ++i)
#pragma unroll
      for (int j = 0; j < 4; ++j)
        acc[i][j] = __builtin_amdgcn_mfma_f32_16x16x32_bf16(a0[i], b0[j], acc[i][j], 0, 0, 0);
    __builtin_amdgcn_s_setprio(0);
    __builtin_amdgcn_s_barrier();
    short8 a1[4];
#pragma unroll
    for (int i = 0; i < 4; ++i)
      a1[i] = *(const short8*)&As[buf][(rw0 + 64 + i * 16 + (lane & 15)) * 32 + rchunk];
    if (t + 2 < NT) {
      stageB(sbuf, kf, 0); stageB(sbuf, kf, 1);
      asm volatile("s_waitcnt vmcnt(4)" ::: "memory");
    } else if (t + 1 < NT) {
      asm volatile("s_waitcnt vmcnt(0)" ::: "memory");
    }
    __builtin_amdgcn_s_barrier();
    __builtin_amdgcn_s_setprio(1);
#pragma unroll
    for (int i = 0; i < 4; ++i)
#pragma unroll
      for (int j = 0; j < 4; ++j)
        acc[4 + i][j] = __builtin_amdgcn_mfma_f32_16x16x32_bf16(a1[i], b0[j], acc[4 + i][j], 0, 0, 0);
    __builtin_amdgcn_s_setprio(0);
    __builtin_amdgcn_s_barrier();
    buf = (buf == 2) ? 0 : buf + 1;
  }

  const int bdir = bn >> 11;
  const int bz = ((bn & 2047) >= 1024);
  const int bncol = bn & 1023;
  ushort* Cp = (bz ? Cz : Cu) + (long)bdir * USLAB;
  ushort* scr = &As[0][0] + w * 1024;            // 16x64 ushort per wave

#pragma unroll
  for (int i = 0; i < 8; ++i) {
#pragma unroll
    for (int r = 0; r < 4; ++r)
#pragma unroll
      for (int j = 0; j < 4; ++j) {
        float v = acc[i][j][r];
        if (bz) v = v * sigmoidf_(v);
        scr[((lane >> 4) * 4 + r) * 64 + j * 16 + (lane & 15)] = f2b(v);
      }
#pragma unroll
    for (int q = 0; q < 2; ++q) {
      int r16 = (lane >> 3) + q * 8;             // 0..15
      short8 pk = *(const short8*)&scr[r16 * 64 + (lane & 7) * 8];
      int m = bm + rw0 + i * 16 + r16;
      int row = bdir ? revrow(m) : m;
      *(short8*)&Cp[(long)row * 1024 + bncol + cw0 + (lane & 7) * 8] = pk;
    }
  }
}

// ---------------- bf16 MFMA GEMM: 2-phase dbuf + T2 swizzle + T1 -----------
// EPI: 0 = fp32 store, 1 = softplus->bf16 (LDS-transposed stores), 4 = bf16
template<int BM, int BN, int RW, int CW, int EPI, int DUALK, int MDIAG>
__global__ __launch_bounds__(256) void gemm_bf16(
    const ushort* __restrict__ A, int lda, const ushort* __restrict__ A2,
    const ushort* __restrict__ B, int ldb, const ushort* __restrict__ B2,
    float* __restrict__ Cf, ushort* __restrict__ Cb, ushort* __restrict__ Cb2,
    int ldc, int K, const float* __restrict__ bias, const float* __restrict__ bias2,
    int b_stride, int revC, int accumC)
{
  constexpr int MI = BM / RW / 16;
  constexpr int NJ = BN / CW / 16;
  __shared__ ushort As[2][BM * 32];
  __shared__ ushort Bs[2][BN * 32];
  const int tid = threadIdx.x;
  const int w = tid >> 6, lane = tid & 63;

  const int nwg = gridDim.x * gridDim.y;
  int bid = blockIdx.y * gridDim.x + blockIdx.x;
  int wgid = (bid & 7) * (nwg >> 3) + (bid >> 3);
  const int bm = (wgid / gridDim.x) * BM;
  const int bn = (wgid % gridDim.x) * BN;

  if (MDIAG) {
    int mdir = (bm >= NROWS) ? 1 : 0;
    B += mdir * b_stride;
    if (mdir) bias = bias2;
  }

  const int rw0 = (w / CW) * (MI * 16);
  const int cw0 = (w % CW) * (NJ * 16);
  const int srow = w * 16 + (lane >> 2);
  const int scol = (((lane & 3) ^ ((lane >> 3) & 3)) << 3);
  const int rchunk = (((lane >> 4) ^ (((lane & 15) >> 1) & 3)) << 3);

  f32x4 acc[MI][NJ] = {};

  auto stage = [&](int buf, int k0) {
    const ushort* Ap = A;
    const ushort* Bp = B;
    int kc = k0;
    bool hi = false;
    if (DUALK && k0 >= (K >> 1)) { Ap = A2; Bp = B2; kc = k0 - (K >> 1); hi = true; }
#pragma unroll
    for (int it = 0; it < BM / 64; ++it) {
      int gm = bm + it * 64 + srow;
      int arow = (DUALK && hi) ? revrow(gm) : gm;
      gload16(Ap + (long)arow * lda + kc + scol, &As[buf][(it * 64 + w * 16) * 32]);
    }
#pragma unroll
    for (int it = 0; it < BN / 64; ++it) {
      int gn = bn + it * 64 + srow;
      gload16(Bp + (long)gn * ldb + kc + scol, &Bs[buf][(it * 64 + w * 16) * 32]);
    }
  };

  stage(0, 0);
  __syncthreads();

  for (int k0 = 0; k0 < K; k0 += 32) {
    int cur = (k0 >> 5) & 1;
    if (k0 + 32 < K) stage(cur ^ 1, k0 + 32);
    short8 a[MI], b[NJ];
#pragma unroll
    for (int i = 0; i < MI; ++i)
      a[i] = *(const short8*)&As[cur][(rw0 + i * 16 + (lane & 15)) * 32 + rchunk];
#pragma unroll
    for (int j = 0; j < NJ; ++j)
      b[j] = *(const short8*)&Bs[cur][(cw0 + j * 16 + (lane & 15)) * 32 + rchunk];
#pragma unroll
    for (int i = 0; i < MI; ++i)
#pragma unroll
      for (int j = 0; j < NJ; ++j)
        acc[i][j] = __builtin_amdgcn_mfma_f32_16x16x32_bf16(a[i], b[j], acc[i][j], 0, 0, 0);
    __syncthreads();
  }

  if (EPI == 1) {
    // LDS-transposed bf16 stores (full 128B lines); NJ*16 == 64 cols/wave
    ushort* scr = &As[0][0] + w * 1024;
#pragma unroll
    for (int i = 0; i < MI; ++i) {
#pragma unroll
      for (int r = 0; r < 4; ++r)
#pragma unroll
        for (int j = 0; j < NJ; ++j) {
          int n = bn + cw0 + j * 16 + (lane & 15);
          float v = softplus_(acc[i][j][r] + bias[n]);
          scr[((lane >> 4) * 4 + r) * 64 + j * 16 + (lane & 15)] = f2b(v);
        }
#pragma unroll
      for (int q = 0; q < 2; ++q) {
        int r16 = (lane >> 3) + q * 8;
        short8 pk = *(const short8*)&scr[r16 * 64 + (lane & 7) * 8];
        int m = bm + rw0 + i * 16 + r16;
        *(short8*)&Cb[(long)m * ldc + bn + cw0 + (lane & 7) * 8] = pk;
      }
    }
  } else {
#pragma unroll
    for (int i = 0; i < MI; ++i)
#pragma unroll
      for (int r = 0; r < 4; ++r) {
        int m = bm + rw0 + i * 16 + (lane >> 4) * 4 + r;
        int crow = revC ? revrow(m) : m;
#pragma unroll
        for (int j = 0; j < NJ; ++j) {
          int n = bn + cw0 + j * 16 + (lane & 15);
          float v = acc[i][j][r];
          if (EPI == 0) {
            float* p = Cf + (long)crow * ldc + n;
            if (accumC) *p += v; else *p = v;
          } else {  // EPI == 4
            Cb[(long)crow * ldc + n] = f2b(v);
          }
        }
      }
  }
}

// ---------------- fused fp32->bf16 converter (x + 8 weight tensors) --------
struct Seg { const float4* s; ushort4* d; int n4; int bstart; };
struct ConvArgs { Seg seg[9]; };

__global__ __launch_bounds__(256) void convert_all(ConvArgs a)
{
  int blk = blockIdx.x;
  int i = 0;
#pragma unroll
  for (int k = 1; k < 9; ++k) if (blk >= a.seg[k].bstart) i = k;
  int idx = (blk - a.seg[i].bstart) * 256 + threadIdx.x;
  if (idx >= a.seg[i].n4) return;
  float4 v = a.seg[i].s[idx];
  ushort4 o;
  o.x = f2b(v.x); o.y = f2b(v.y); o.z = f2b(v.z); o.w = f2b(v.w);
  a.seg[i].d[idx] = o;
}

// ------------- conv1d(k=4) + bias + silu, both dirs (4 d/thread) -----------
__global__ __launch_bounds__(256) void conv_silu(
    const ushort* __restrict__ u_bf,
    const float* __restrict__ cw_f, const float* __restrict__ cw_b,
    const float* __restrict__ cb_f, const float* __restrict__ cb_b,
    ushort* __restrict__ uc_bf)
{
  long i = (long)blockIdx.x * 256 + threadIdx.x;
  int dir = (int)(i >> 21);
  int r = (int)(i >> 8) & 8191;
  int d0 = ((int)i & 255) << 2;
  int t = r & (SEQ - 1);
  const float* cw = dir ? cw_b : cw_f;
  const float* cb = dir ? cb_b : cb_f;
  const ushort* p = u_bf + dir * USLAB + (long)r * D_INNER + d0;
  ushort4 u0 = *(const ushort4*)p;
  ushort4 u1 = (t >= 1) ? *(const ushort4*)(p - 1024) : ushort4{0, 0, 0, 0};
  ushort4 u2 = (t >= 2) ? *(const ushort4*)(p - 2048) : ushort4{0, 0, 0, 0};
  ushort4 u3 = (t >= 3) ? *(const ushort4*)(p - 3072) : ushort4{0, 0, 0, 0};
  float4 bb = *(const float4*)(cb + d0);
  float ub0[4] = {b2f(u0.x), b2f(u0.y), b2f(u0.z), b2f(u0.w)};
  float ub1[4] = {b2f(u1.x), b2f(u1.y), b2f(u1.z), b2f(u1.w)};
  float ub2[4] = {b2f(u2.x), b2f(u2.y), b2f(u2.z), b2f(u2.w)};
  float ub3[4] = {b2f(u3.x), b2f(u3.y), b2f(u3.z), b2f(u3.w)};
  float bbv[4] = {bb.x, bb.y, bb.z, bb.w};
  ushort ov[4];
#pragma unroll
  for (int j = 0; j < 4; ++j) {
    float4 wj = *(const float4*)(cw + (d0 + j) * 4);
    float acc = bbv[j];
    acc = fmaf(wj.w, ub0[j], acc);
    acc = fmaf(wj.z, ub1[j], acc);
    acc = fmaf(wj.y, ub2[j], acc);
    acc = fmaf(wj.x, ub3[j], acc);
    ov[j] = f2b(acc * sigmoidf_(acc));
  }
  ushort4 o;
  o.x = ov[0]; o.y = ov[1]; o.z = ov[2]; o.w = ov[3];
  *(ushort4*)(uc_bf + dir * USLAB + (long)r * D_INNER + d0) = o;
}

// Decay powers E^(s+1), s=0..15, from E = exp(-dt).
#define EP_FAST(dt, Ep)                                        \
  {                                                            \
    float E1 = __expf(-(dt));                                  \
    float E2 = E1 * E1, E4 = E2 * E2, E8 = E4 * E4;            \
    Ep[0] = E1;  Ep[1] = E2;      Ep[2] = E2 * E1;             \
    Ep[3] = E4;  Ep[4] = E4 * E1; Ep[5] = E4 * E2;             \
    Ep[6] = E4 * Ep[2]; Ep[7] = E8;  Ep[8] = E8 * E1;          \
    Ep[9] = E8 * E2; Ep[10] = E8 * Ep[2]; Ep[11] = E8 * E4;    \
    Ep[12] = E8 * Ep[4]; Ep[13] = E8 * Ep[5];                  \
    Ep[14] = E8 * Ep[6]; Ep[15] = E8 * E8;                     \
  }

__device__ __forceinline__ bool a_is_arange(const float* Ar) {
  bool ok = true;
#pragma unroll
  for (int s = 0; s < D_STATE; ++s)
    ok = ok && (fabsf(Ar[s] + (float)(s + 1)) <= 1e-3f * (float)(s + 1));
  return ok;
}

// ---------------- chunked selective scan (both dirs in one grid) -----------
__global__ __launch_bounds__(256) void scan_partA(
    const ushort* __restrict__ delta_bf,
    const ushort* __restrict__ ucv_bf,
    const ushort* __restrict__ dblb,
    const float* __restrict__ A_log_f, const float* __restrict__ A_log_b,
    ushort* __restrict__ hend,
    float* __restrict__ dtsum_buf)
{
  __shared__ float bc[CL][16];
  long idx = (long)blockIdx.x * 256 + threadIdx.x;
  int d = (int)idx & 1023;
  int c = ((int)idx >> 10) & (CH - 1);
  int b = ((int)idx >> 16) & 7;
  int dir = (int)(idx >> 19);
  const long r0 = (long)b * SEQ + c * CL;
  const ushort* dblp = dblb + (long)dir * NROWS * 64;
  {
    int tt = threadIdx.x >> 4, ss = threadIdx.x & 15;
    bc[tt][ss] = b2f(dblp[(r0 + tt) * 64 + 32 + ss]);
  }
  const float* Alog = dir ? A_log_b : A_log_f;
  const ushort* dp = delta_bf + dir * USLAB;
  const ushort* up = ucv_bf + dir * USLAB;
  float Ar[D_STATE];
#pragma unroll
  for (int s = 0; s < D_STATE; ++s) Ar[s] = -__expf(Alog[d * D_STATE + s]);
  const bool fast = a_is_arange(Ar);
  float h[D_STATE] = {0.f};
  float dtsum = 0.f;
  __syncthreads();

  if (fast) {
    for (int t = 0; t < CL; ++t) {
      long r = r0 + t;
      float dt = b2f(dp[r * 1024 + d]);
      float u  = b2f(up[r * 1024 + d]);
      float du = dt * u;
      dtsum += dt;
      float Ep[16];
      EP_FAST(dt, Ep);
#pragma unroll
      for (int s = 0; s < D_STATE; ++s)
        h[s] = fmaf(h[s], Ep[s], du * bc[t][s]);
    }
  } else {
    for (int t = 0; t < CL; ++t) {
      long r = r0 + t;
      float dt = b2f(dp[r * 1024 + d]);
      float u  = b2f(up[r * 1024 + d]);
      float du = dt * u;
      dtsum += dt;
#pragma unroll
      for (int s = 0; s < D_STATE; ++s)
        h[s] = fmaf(h[s], __expf(dt * Ar[s]), du * bc[t][s]);
    }
  }
  long base = ((long)((dir * 8 + b) * CH + c) * D_STATE) * 1024 + d;
#pragma unroll
  for (int s = 0; s < D_STATE; ++s) hend[base + s * 1024] = f2b(h[s]);
  dtsum_buf[(long)((dir * 8 + b) * CH + c) * 1024 + d] = dtsum;
}

__global__ __launch_bounds__(256) void scan_partB(
    ushort* __restrict__ hend,
    const float* __restrict__ dtsum_buf,
    const float* __restrict__ A_log_f, const float* __restrict__ A_log_b)
{
  long idx = (long)blockIdx.x * 256 + threadIdx.x;
  int d = (int)idx & 1023;
  int s = ((int)idx >> 10) & 15;
  int b = ((int)idx >> 14) & 7;
  int dir = (int)(idx >> 17);
  const float* Alog = dir ? A_log_b : A_log_f;
  float Ars = -__expf(Alog[d * D_STATE + s]);
  float H = 0.f;
  for (int c = 0; c < CH; ++c) {
    long off = ((long)((dir * 8 + b) * CH + c) * D_STATE + s) * 1024 + d;
    float he = b2f(hend[off]);
    float P = __expf(Ars * dtsum_buf[(long)((dir * 8 + b) * CH + c) * 1024 + d]);
    hend[off] = f2b(H);
    H = fmaf(P, H, he);
  }
}

__global__ __launch_bounds__(256) void scan_partC(
    const ushort* __restrict__ delta_bf,
    const ushort* __restrict__ ucv_bf,
    const ushort* __restrict__ dblb,
    const float* __restrict__ A_log_f, const float* __restrict__ A_log_b,
    const float* __restrict__ Dp_f, const float* __restrict__ Dp_b,
    const ushort* __restrict__ zsilu_bf,
    const ushort* __restrict__ hinit,
    ushort* __restrict__ ydz_bf)
{
  __shared__ float bc[CL][32];
  long idx = (long)blockIdx.x * 256 + threadIdx.x;
  int d = (int)idx & 1023;
  int c = ((int)idx >> 10) & (CH - 1);
  int b = ((int)idx >> 16) & 7;
  int dir = (int)(idx >> 19);
  const long r0 = (long)b * SEQ + c * CL;
  const ushort* dblp = dblb + (long)dir * NROWS * 64;
  {
    int tt = threadIdx.x >> 4, cc = (threadIdx.x & 15) * 2;
    ushort2 v = *(const ushort2*)&dblp[(r0 + tt) * 64 + 32 + cc];
    bc[tt][cc] = b2f(v.x); bc[tt][cc + 1] = b2f(v.y);
  }
  const float* Alog = dir ? A_log_b : A_log_f;
  const ushort* dp = delta_bf + dir * USLAB;
  const ushort* up = ucv_bf + dir * USLAB;
  const ushort* zp = zsilu_bf + dir * USLAB;
  ushort* yp = ydz_bf + dir * USLAB;
  float Ar[D_STATE];
#pragma unroll
  for (int s = 0; s < D_STATE; ++s) Ar[s] = -__expf(Alog[d * D_STATE + s]);
  const bool fast = a_is_arange(Ar);
  float h[D_STATE];
  long base = ((long)((dir * 8 + b) * CH + c) * D_STATE) * 1024 + d;
#pragma unroll
  for (int s = 0; s < D_STATE; ++s) h[s] = b2f(hinit[base + s * 1024]);
  float Dd = (dir ? Dp_b : Dp_f)[d];
  __syncthreads();

  if (fast) {
    for (int t = 0; t < CL; ++t) {
      long r = r0 + t;
      float dt = b2f(dp[r * 1024 + d]);
      float u  = b2f(up[r * 1024 + d]);
      float du = dt * u;
      float Ep[16];
      EP_FAST(dt, Ep);
      float y = 0.f;
#pragma unroll
      for (int s = 0; s < D_STATE; ++s) {
        h[s] = fmaf(h[s], Ep[s], du * bc[t][s]);
        y = fmaf(h[s], bc[t][16 + s], y);
      }
      float zs = b2f(zp[r * 1024 + d]);
      float yv = fmaf(u, Dd, y);
      yp[r * 1024 + d] = f2b(yv * zs);
    }
  } else {
    for (int t = 0; t < CL; ++t) {
      long r = r0 + t;
      float dt = b2f(dp[r * 1024 + d]);
      float u  = b2f(up[r * 1024 + d]);
      float du = dt * u;
      float y = 0.f;
#pragma unroll
      for (int s = 0; s < D_STATE; ++s) {
        h[s] = fmaf(h[s], __expf(dt * Ar[s]), du * bc[t][s]);
        y = fmaf(h[s], bc[t][16 + s], y);
      }
      float zs = b2f(zp[r * 1024 + d]);
      float yv = fmaf(u, Dd, y);
      yp[r * 1024 + d] = f2b(yv * zs);
    }
  }
}

extern "C" void kernel_launch(void* const* d_in, const int* in_sizes, int n_in,
                              void* d_out, int out_size, void* d_ws, size_t ws_size,
                              hipStream_t stream)
{
  const float* x = (const float*)d_in[0];
  float* out = (float*)d_out;
  char* ws = (char*)d_ws;
  ushort* zsilu  = (ushort*)(ws);                     // 32 MiB
  ushort* ucv    = (ushort*)(ws + (32ul << 20));      // 32 MiB (=ydz)
  ushort* u_bf   = (ushort*)(ws + (64ul << 20));      // 32 MiB (=delta)
  ushort* hend   = (ushort*)(ws + (96ul << 20));      // 32 MiB
  float*  dtsum  = (float*)(ws + (128ul << 20));      //  4 MiB
  ushort* dblb   = (ushort*)(ws + (132ul << 20));     //  2 MiB
  ushort* out_wb = (ushort*)(ws + (134ul << 20));     //  2 MiB
  ushort* xbf    = hend;                              // transient in hend slab
  ushort* in_wb  = hend + (8ul << 19);
  ushort* xp_wb  = hend + (12ul << 19);
  ushort* dt_wb  = xp_wb + 131072;
  ushort* delta  = u_bf;
  ushort* ydz    = ucv;

  ConvArgs ca;
  int bcur = 0, si = 0;
  auto addseg = [&](const float* s, ushort* d, int nelem) {
    ca.seg[si].s = (const float4*)s; ca.seg[si].d = (ushort4*)d;
    ca.seg[si].n4 = nelem / 4; ca.seg[si].bstart = bcur;
    bcur += (nelem / 4 + 255) / 256; ++si;
  };
  addseg(x, xbf, NROWS * D_MODEL);
  addseg((const float*)d_in[1], in_wb, 2048 * 512);
  addseg((const float*)d_in[10], in_wb + 2048 * 512, 2048 * 512);
  addseg((const float*)d_in[9], out_wb, 512 * 1024);
  addseg((const float*)d_in[18], out_wb + 512 * 1024, 512 * 1024);
  addseg((const float*)d_in[4], xp_wb, 64 * 1024);
  addseg((const float*)d_in[13], xp_wb + 65536, 64 * 1024);
  addseg((const float*)d_in[5], dt_wb, 1024 * 32);
  addseg((const float*)d_in[14], dt_wb + 32768, 1024 * 32);

  dim3 blk(256);
  convert_all<<<dim3(bcur), blk, 0, stream>>>(ca);

  // 1) merged in_proj (vectorized epilogue)
  inproj256<<<dim3(4096 / 256, NROWS / 256), dim3(512), 0, stream>>>(
      xbf, D_MODEL, in_wb, D_MODEL, u_bf, zsilu, D_MODEL);
  // 2) conv + silu, both dirs
  conv_silu<<<dim3(2 * NROWS), blk, 0, stream>>>(
      u_bf, (const float*)d_in[2], (const float*)d_in[11],
      (const float*)d_in[3], (const float*)d_in[12], ucv);
  // 3) x_proj, both dirs block-diag
  gemm_bf16<64, 64, 2, 2, 4, 0, 1><<<dim3(1, 256), blk, 0, stream>>>(
      ucv, D_INNER, nullptr, xp_wb, D_INNER, nullptr,
      nullptr, dblb, nullptr, 64, D_INNER, nullptr, nullptr, 65536, 0, 0);
  // 4) dt_proj + softplus, both dirs block-diag (vectorized epilogue)
  gemm_bf16<128, 128, 2, 2, 1, 0, 1><<<dim3(8, 128), blk, 0, stream>>>(
      dblb, 64, nullptr, dt_wb, DT_RANK, nullptr,
      nullptr, delta, nullptr, D_INNER, DT_RANK,
      (const float*)d_in[6], (const float*)d_in[15], 32768, 0, 0);
  // 5) chunked scan, both dirs
  const float* Alf = (const float*)d_in[7];
  const float* Alb = (const float*)d_in[16];
  scan_partA<<<dim3(2 * BATCH * CH * 1024 / 256), blk, 0, stream>>>(
      delta, ucv, dblb, Alf, Alb, hend, dtsum);
  scan_partB<<<dim3(2 * BATCH * 16 * 1024 / 256), blk, 0, stream>>>(
      hend, dtsum, Alf, Alb);
  scan_partC<<<dim3(2 * BATCH * CH * 1024 / 256), blk, 0, stream>>>(
      delta, ucv, dblb, Alf, Alb,
      (const float*)d_in[8], (const float*)d_in[17], zsilu, hend, ydz);
  // 6) out_proj, both dirs in one K=2048 dispatch
  gemm_bf16<128, 128, 2, 2, 0, 1, 0><<<dim3(4, 64), blk, 0, stream>>>(
      ydz, D_INNER, ydz + USLAB, out_wb, D_INNER, out_wb + 512 * 1024,
      out, nullptr, nullptr, D_MODEL, 2 * D_INNER, nullptr, nullptr, 0, 0, 0);
}

// Round 17
// 247.250 us; speedup vs baseline: 1.2443x; 1.0402x over previous
//
#include <hip/hip_runtime.h>
#include <math.h>

#define BATCH 8
#define SEQ 1024
#define D_MODEL 512
#define D_INNER 1024
#define D_STATE 16
#define DT_RANK 32
#define NROWS (BATCH * SEQ)   // 8192
#define CH 64                 // chunks per sequence
#define CL 16                 // chunk length
#define USLAB 8388608l        // 8192*1024 elems (one dir slab)

typedef short short8 __attribute__((ext_vector_type(8)));
typedef float f32x4 __attribute__((ext_vector_type(4)));

__device__ __forceinline__ float sigmoidf_(float x) { return 1.f / (1.f + __expf(-x)); }

__device__ __forceinline__ float softplus_(float v) {
  return (v > 20.f) ? v : __logf(1.f + __expf(v));
}

__device__ __forceinline__ ushort f2b(float f) {  // fp32 -> bf16 RNE
  uint u = __float_as_uint(f);
  return (ushort)((u + 0x7FFFu + ((u >> 16) & 1u)) >> 16);
}
__device__ __forceinline__ float b2f(ushort u) {
  return __uint_as_float(((uint)u) << 16);
}

__device__ __forceinline__ void gload16(const ushort* g, const ushort* l) {
  __builtin_amdgcn_global_load_lds(
      (const __attribute__((address_space(1))) void*)g,
      (__attribute__((address_space(3))) void*)l, 16, 0, 0);
}

__device__ __forceinline__ int revrow(int m) {
  return (m & ~1023) | (1023 - (m & 1023));
}

// ========== in_proj: 256x128 tile, 8 waves, counted-vmcnt, 2 blocks/CU =====
// 72 KB LDS (3 bufs) -> 2 blocks/CU for inter-block fixed-cost overlap.
// One barrier per K-tile; vmcnt(3) certifies tile t+1 before the barrier.
__global__ __launch_bounds__(512, 4) void inproj256(
    const ushort* __restrict__ A, int lda,      // [8192][512]
    const ushort* __restrict__ B, int ldb,      // [4096][512]
    ushort* __restrict__ Cu, ushort* __restrict__ Cz,
    int K)
{
  __shared__ ushort As[3][256 * 32];            // 48 KB
  __shared__ ushort Bs[3][128 * 32];            // 24 KB
  const int tid = threadIdx.x;
  const int w = tid >> 6, lane = tid & 63;

  const int nwg = gridDim.x * gridDim.y;        // 1024, %8 == 0
  int bid = blockIdx.y * gridDim.x + blockIdx.x;
  int wgid = (bid & 7) * (nwg >> 3) + (bid >> 3);
  const int bm = (wgid / gridDim.x) * 256;
  const int bn = (wgid % gridDim.x) * 128;

  const int wr = w >> 1, wc = w & 1;            // 4x2 wave grid
  const int rw0 = wr * 64, cw0 = wc * 64;       // per-wave 64x64 output
  const int srow = w * 16 + (lane >> 2);        // 8 waves cover 128 rows
  const int scol = (((lane & 3) ^ ((lane >> 3) & 3)) << 3);
  const int rchunk = (((lane >> 4) ^ (((lane & 15) >> 1) & 3)) << 3);

  f32x4 acc[4][4] = {};

  auto stage = [&](int buf, int k0) {
#pragma unroll
    for (int half = 0; half < 2; ++half) {      // A: 256 rows
      int gm = bm + half * 128 + srow;
      gload16(A + (long)gm * lda + k0 + scol, &As[buf][(half * 128 + w * 16) * 32]);
    }
    int gn = bn + srow;                         // B: 128 rows
    gload16(B + (long)gn * ldb + k0 + scol, &Bs[buf][(w * 16) * 32]);
  };

  const int NT = K >> 5;                        // 16 for K=512
  stage(0, 0);
  stage(1, 32);
  asm volatile("s_waitcnt vmcnt(3)" ::: "memory");   // tile 0 certified
  __builtin_amdgcn_s_barrier();

  int buf = 0;
  for (int t = 0; t < NT; ++t) {
    short8 a[4], b[4];
#pragma unroll
    for (int i = 0; i < 4; ++i)
      a[i] = *(const short8*)&As[buf][(rw0 + i * 16 + (lane & 15)) * 32 + rchunk];
#pragma unroll
    for (int j = 0; j < 4; ++j)
      b[j] = *(const short8*)&Bs[buf][(cw0 + j * 16 + (lane & 15)) * 32 + rchunk];
    int sbuf = (buf >= 1) ? buf - 1 : buf + 2;  // (buf+2)%3
    if (t + 2 < NT) {
      stage(sbuf, (t + 2) << 5);
      asm volatile("s_waitcnt vmcnt(3)" ::: "memory");   // t+1 certified
    } else if (t + 1 < NT) {
      asm volatile("s_waitcnt vmcnt(0)" ::: "memory");
    }
    __builtin_amdgcn_s_barrier();
    __builtin_amdgcn_s_setprio(1);
#pragma unroll
    for (int i = 0; i < 4; ++i)
#pragma unroll
      for (int j = 0; j < 4; ++j)
        acc[i][j] = __builtin_amdgcn_mfma_f32_16x16x32_bf16(a[i], b[j], acc[i][j], 0, 0, 0);
    __builtin_amdgcn_s_setprio(0);
    buf = (buf == 2) ? 0 : buf + 1;
  }
  __builtin_amdgcn_s_barrier();                 // protect scr overlay of As[0]

  const int bdir = bn >> 11;
  const int bz = ((bn & 2047) >= 1024);
  const int bncol = bn & 1023;
  ushort* Cp = (bz ? Cz : Cu) + (long)bdir * USLAB;
  ushort* scr = &As[0][0] + w * 1024;           // 16x64 ushort per wave

#pragma unroll
  for (int i = 0; i < 4; ++i) {
#pragma unroll
    for (int r = 0; r < 4; ++r)
#pragma unroll
      for (int j = 0; j < 4; ++j) {
        float v = acc[i][j][r];
        if (bz) v = v * sigmoidf_(v);
        scr[((lane >> 4) * 4 + r) * 64 + j * 16 + (lane & 15)] = f2b(v);
      }
#pragma unroll
    for (int q = 0; q < 2; ++q) {
      int r16 = (lane >> 3) + q * 8;
      short8 pk = *(const short8*)&scr[r16 * 64 + (lane & 7) * 8];
      int m = bm + rw0 + i * 16 + r16;
      int row = bdir ? revrow(m) : m;
      *(short8*)&Cp[(long)row * 1024 + bncol + cw0 + (lane & 7) * 8] = pk;
    }
  }
}

// ---------------- bf16 MFMA GEMM: 2-phase dbuf + T2 swizzle + T1 -----------
// EPI: 0 = fp32 store, 1 = softplus->bf16 (LDS-transposed stores), 4 = bf16
template<int BM, int BN, int RW, int CW, int EPI, int DUALK, int MDIAG>
__global__ __launch_bounds__(256) void gemm_bf16(
    const ushort* __restrict__ A, int lda, const ushort* __restrict__ A2,
    const ushort* __restrict__ B, int ldb, const ushort* __restrict__ B2,
    float* __restrict__ Cf, ushort* __restrict__ Cb, ushort* __restrict__ Cb2,
    int ldc, int K, const float* __restrict__ bias, const float* __restrict__ bias2,
    int b_stride, int revC, int accumC)
{
  constexpr int MI = BM / RW / 16;
  constexpr int NJ = BN / CW / 16;
  __shared__ ushort As[2][BM * 32];
  __shared__ ushort Bs[2][BN * 32];
  const int tid = threadIdx.x;
  const int w = tid >> 6, lane = tid & 63;

  const int nwg = gridDim.x * gridDim.y;
  int bid = blockIdx.y * gridDim.x + blockIdx.x;
  int wgid = (bid & 7) * (nwg >> 3) + (bid >> 3);
  const int bm = (wgid / gridDim.x) * BM;
  const int bn = (wgid % gridDim.x) * BN;

  if (MDIAG) {
    int mdir = (bm >= NROWS) ? 1 : 0;
    B += mdir * b_stride;
    if (mdir) bias = bias2;
  }

  const int rw0 = (w / CW) * (MI * 16);
  const int cw0 = (w % CW) * (NJ * 16);
  const int srow = w * 16 + (lane >> 2);
  const int scol = (((lane & 3) ^ ((lane >> 3) & 3)) << 3);
  const int rchunk = (((lane >> 4) ^ (((lane & 15) >> 1) & 3)) << 3);

  f32x4 acc[MI][NJ] = {};

  auto stage = [&](int buf, int k0) {
    const ushort* Ap = A;
    const ushort* Bp = B;
    int kc = k0;
    bool hi = false;
    if (DUALK && k0 >= (K >> 1)) { Ap = A2; Bp = B2; kc = k0 - (K >> 1); hi = true; }
#pragma unroll
    for (int it = 0; it < BM / 64; ++it) {
      int gm = bm + it * 64 + srow;
      int arow = (DUALK && hi) ? revrow(gm) : gm;
      gload16(Ap + (long)arow * lda + kc + scol, &As[buf][(it * 64 + w * 16) * 32]);
    }
#pragma unroll
    for (int it = 0; it < BN / 64; ++it) {
      int gn = bn + it * 64 + srow;
      gload16(Bp + (long)gn * ldb + kc + scol, &Bs[buf][(it * 64 + w * 16) * 32]);
    }
  };

  stage(0, 0);
  __syncthreads();

  for (int k0 = 0; k0 < K; k0 += 32) {
    int cur = (k0 >> 5) & 1;
    if (k0 + 32 < K) stage(cur ^ 1, k0 + 32);
    short8 a[MI], b[NJ];
#pragma unroll
    for (int i = 0; i < MI; ++i)
      a[i] = *(const short8*)&As[cur][(rw0 + i * 16 + (lane & 15)) * 32 + rchunk];
#pragma unroll
    for (int j = 0; j < NJ; ++j)
      b[j] = *(const short8*)&Bs[cur][(cw0 + j * 16 + (lane & 15)) * 32 + rchunk];
#pragma unroll
    for (int i = 0; i < MI; ++i)
#pragma unroll
      for (int j = 0; j < NJ; ++j)
        acc[i][j] = __builtin_amdgcn_mfma_f32_16x16x32_bf16(a[i], b[j], acc[i][j], 0, 0, 0);
    __syncthreads();
  }

  if (EPI == 1) {
    ushort* scr = &As[0][0] + w * 1024;
#pragma unroll
    for (int i = 0; i < MI; ++i) {
#pragma unroll
      for (int r = 0; r < 4; ++r)
#pragma unroll
        for (int j = 0; j < NJ; ++j) {
          int n = bn + cw0 + j * 16 + (lane & 15);
          float v = softplus_(acc[i][j][r] + bias[n]);
          scr[((lane >> 4) * 4 + r) * 64 + j * 16 + (lane & 15)] = f2b(v);
        }
#pragma unroll
      for (int q = 0; q < 2; ++q) {
        int r16 = (lane >> 3) + q * 8;
        short8 pk = *(const short8*)&scr[r16 * 64 + (lane & 7) * 8];
        int m = bm + rw0 + i * 16 + r16;
        *(short8*)&Cb[(long)m * ldc + bn + cw0 + (lane & 7) * 8] = pk;
      }
    }
  } else {
#pragma unroll
    for (int i = 0; i < MI; ++i)
#pragma unroll
      for (int r = 0; r < 4; ++r) {
        int m = bm + rw0 + i * 16 + (lane >> 4) * 4 + r;
        int crow = revC ? revrow(m) : m;
#pragma unroll
        for (int j = 0; j < NJ; ++j) {
          int n = bn + cw0 + j * 16 + (lane & 15);
          float v = acc[i][j][r];
          if (EPI == 0) {
            float* p = Cf + (long)crow * ldc + n;
            if (accumC) *p += v; else *p = v;
          } else {  // EPI == 4
            Cb[(long)crow * ldc + n] = f2b(v);
          }
        }
      }
  }
}

// ---------------- fused fp32->bf16 converter (x + 8 weight tensors) --------
struct Seg { const float4* s; ushort4* d; int n4; int bstart; };
struct ConvArgs { Seg seg[9]; };

__global__ __launch_bounds__(256) void convert_all(ConvArgs a)
{
  int blk = blockIdx.x;
  int i = 0;
#pragma unroll
  for (int k = 1; k < 9; ++k) if (blk >= a.seg[k].bstart) i = k;
  int idx = (blk - a.seg[i].bstart) * 256 + threadIdx.x;
  if (idx >= a.seg[i].n4) return;
  float4 v = a.seg[i].s[idx];
  ushort4 o;
  o.x = f2b(v.x); o.y = f2b(v.y); o.z = f2b(v.z); o.w = f2b(v.w);
  a.seg[i].d[idx] = o;
}

// ------------- conv1d(k=4) + bias + silu, both dirs (4 d/thread) -----------
__global__ __launch_bounds__(256) void conv_silu(
    const ushort* __restrict__ u_bf,
    const float* __restrict__ cw_f, const float* __restrict__ cw_b,
    const float* __restrict__ cb_f, const float* __restrict__ cb_b,
    ushort* __restrict__ uc_bf)
{
  long i = (long)blockIdx.x * 256 + threadIdx.x;
  int dir = (int)(i >> 21);
  int r = (int)(i >> 8) & 8191;
  int d0 = ((int)i & 255) << 2;
  int t = r & (SEQ - 1);
  const float* cw = dir ? cw_b : cw_f;
  const float* cb = dir ? cb_b : cb_f;
  const ushort* p = u_bf + dir * USLAB + (long)r * D_INNER + d0;
  ushort4 u0 = *(const ushort4*)p;
  ushort4 u1 = (t >= 1) ? *(const ushort4*)(p - 1024) : ushort4{0, 0, 0, 0};
  ushort4 u2 = (t >= 2) ? *(const ushort4*)(p - 2048) : ushort4{0, 0, 0, 0};
  ushort4 u3 = (t >= 3) ? *(const ushort4*)(p - 3072) : ushort4{0, 0, 0, 0};
  float4 bb = *(const float4*)(cb + d0);
  float ub0[4] = {b2f(u0.x), b2f(u0.y), b2f(u0.z), b2f(u0.w)};
  float ub1[4] = {b2f(u1.x), b2f(u1.y), b2f(u1.z), b2f(u1.w)};
  float ub2[4] = {b2f(u2.x), b2f(u2.y), b2f(u2.z), b2f(u2.w)};
  float ub3[4] = {b2f(u3.x), b2f(u3.y), b2f(u3.z), b2f(u3.w)};
  float bbv[4] = {bb.x, bb.y, bb.z, bb.w};
  ushort ov[4];
#pragma unroll
  for (int j = 0; j < 4; ++j) {
    float4 wj = *(const float4*)(cw + (d0 + j) * 4);
    float acc = bbv[j];
    acc = fmaf(wj.w, ub0[j], acc);
    acc = fmaf(wj.z, ub1[j], acc);
    acc = fmaf(wj.y, ub2[j], acc);
    acc = fmaf(wj.x, ub3[j], acc);
    ov[j] = f2b(acc * sigmoidf_(acc));
  }
  ushort4 o;
  o.x = ov[0]; o.y = ov[1]; o.z = ov[2]; o.w = ov[3];
  *(ushort4*)(uc_bf + dir * USLAB + (long)r * D_INNER + d0) = o;
}

// Decay powers E^(s+1), s=0..15, from E = exp(-dt).
#define EP_FAST(dt, Ep)                                        \
  {                                                            \
    float E1 = __expf(-(dt));                                  \
    float E2 = E1 * E1, E4 = E2 * E2, E8 = E4 * E4;            \
    Ep[0] = E1;  Ep[1] = E2;      Ep[2] = E2 * E1;             \
    Ep[3] = E4;  Ep[4] = E4 * E1; Ep[5] = E4 * E2;             \
    Ep[6] = E4 * Ep[2]; Ep[7] = E8;  Ep[8] = E8 * E1;          \
    Ep[9] = E8 * E2; Ep[10] = E8 * Ep[2]; Ep[11] = E8 * E4;    \
    Ep[12] = E8 * Ep[4]; Ep[13] = E8 * Ep[5];                  \
    Ep[14] = E8 * Ep[6]; Ep[15] = E8 * E8;                     \
  }

__device__ __forceinline__ bool a_is_arange(const float* Ar) {
  bool ok = true;
#pragma unroll
  for (int s = 0; s < D_STATE; ++s)
    ok = ok && (fabsf(Ar[s] + (float)(s + 1)) <= 1e-3f * (float)(s + 1));
  return ok;
}

// ---------------- chunked selective scan (both dirs in one grid) -----------
__global__ __launch_bounds__(256) void scan_partA(
    const ushort* __restrict__ delta_bf,
    const ushort* __restrict__ ucv_bf,
    const ushort* __restrict__ dblb,
    const float* __restrict__ A_log_f, const float* __restrict__ A_log_b,
    ushort* __restrict__ hend,
    float* __restrict__ dtsum_buf)
{
  __shared__ float bc[CL][16];
  long idx = (long)blockIdx.x * 256 + threadIdx.x;
  int d = (int)idx & 1023;
  int c = ((int)idx >> 10) & (CH - 1);
  int b = ((int)idx >> 16) & 7;
  int dir = (int)(idx >> 19);
  const long r0 = (long)b * SEQ + c * CL;
  const ushort* dblp = dblb + (long)dir * NROWS * 64;
  {
    int tt = threadIdx.x >> 4, ss = threadIdx.x & 15;
    bc[tt][ss] = b2f(dblp[(r0 + tt) * 64 + 32 + ss]);
  }
  const float* Alog = dir ? A_log_b : A_log_f;
  const ushort* dp = delta_bf + dir * USLAB;
  const ushort* up = ucv_bf + dir * USLAB;
  float Ar[D_STATE];
#pragma unroll
  for (int s = 0; s < D_STATE; ++s) Ar[s] = -__expf(Alog[d * D_STATE + s]);
  const bool fast = a_is_arange(Ar);
  float h[D_STATE] = {0.f};
  float dtsum = 0.f;
  __syncthreads();

  if (fast) {
    for (int t = 0; t < CL; ++t) {
      long r = r0 + t;
      float dt = b2f(dp[r * 1024 + d]);
      float u  = b2f(up[r * 1024 + d]);
      float du = dt * u;
      dtsum += dt;
      float Ep[16];
      EP_FAST(dt, Ep);
#pragma unroll
      for (int s = 0; s < D_STATE; ++s)
        h[s] = fmaf(h[s], Ep[s], du * bc[t][s]);
    }
  } else {
    for (int t = 0; t < CL; ++t) {
      long r = r0 + t;
      float dt = b2f(dp[r * 1024 + d]);
      float u  = b2f(up[r * 1024 + d]);
      float du = dt * u;
      dtsum += dt;
#pragma unroll
      for (int s = 0; s < D_STATE; ++s)
        h[s] = fmaf(h[s], __expf(dt * Ar[s]), du * bc[t][s]);
    }
  }
  long base = ((long)((dir * 8 + b) * CH + c) * D_STATE) * 1024 + d;
#pragma unroll
  for (int s = 0; s < D_STATE; ++s) hend[base + s * 1024] = f2b(h[s]);
  dtsum_buf[(long)((dir * 8 + b) * CH + c) * 1024 + d] = dtsum;
}

__global__ __launch_bounds__(256) void scan_partB(
    ushort* __restrict__ hend,
    const float* __restrict__ dtsum_buf,
    const float* __restrict__ A_log_f, const float* __restrict__ A_log_b)
{
  long idx = (long)blockIdx.x * 256 + threadIdx.x;
  int d = (int)idx & 1023;
  int s = ((int)idx >> 10) & 15;
  int b = ((int)idx >> 14) & 7;
  int dir = (int)(idx >> 17);
  const float* Alog = dir ? A_log_b : A_log_f;
  float Ars = -__expf(Alog[d * D_STATE + s]);
  float H = 0.f;
  for (int c = 0; c < CH; ++c) {
    long off = ((long)((dir * 8 + b) * CH + c) * D_STATE + s) * 1024 + d;
    float he = b2f(hend[off]);
    float P = __expf(Ars * dtsum_buf[(long)((dir * 8 + b) * CH + c) * 1024 + d]);
    hend[off] = f2b(H);
    H = fmaf(P, H, he);
  }
}

__global__ __launch_bounds__(256) void scan_partC(
    const ushort* __restrict__ delta_bf,
    const ushort* __restrict__ ucv_bf,
    const ushort* __restrict__ dblb,
    const float* __restrict__ A_log_f, const float* __restrict__ A_log_b,
    const float* __restrict__ Dp_f, const float* __restrict__ Dp_b,
    const ushort* __restrict__ zsilu_bf,
    const ushort* __restrict__ hinit,
    ushort* __restrict__ ydz_bf)
{
  __shared__ float bc[CL][32];
  long idx = (long)blockIdx.x * 256 + threadIdx.x;
  int d = (int)idx & 1023;
  int c = ((int)idx >> 10) & (CH - 1);
  int b = ((int)idx >> 16) & 7;
  int dir = (int)(idx >> 19);
  const long r0 = (long)b * SEQ + c * CL;
  const ushort* dblp = dblb + (long)dir * NROWS * 64;
  {
    int tt = threadIdx.x >> 4, cc = (threadIdx.x & 15) * 2;
    ushort2 v = *(const ushort2*)&dblp[(r0 + tt) * 64 + 32 + cc];
    bc[tt][cc] = b2f(v.x); bc[tt][cc + 1] = b2f(v.y);
  }
  const float* Alog = dir ? A_log_b : A_log_f;
  const ushort* dp = delta_bf + dir * USLAB;
  const ushort* up = ucv_bf + dir * USLAB;
  const ushort* zp = zsilu_bf + dir * USLAB;
  ushort* yp = ydz_bf + dir * USLAB;
  float Ar[D_STATE];
#pragma unroll
  for (int s = 0; s < D_STATE; ++s) Ar[s] = -__expf(Alog[d * D_STATE + s]);
  const bool fast = a_is_arange(Ar);
  float h[D_STATE];
  long base = ((long)((dir * 8 + b) * CH + c) * D_STATE) * 1024 + d;
#pragma unroll
  for (int s = 0; s < D_STATE; ++s) h[s] = b2f(hinit[base + s * 1024]);
  float Dd = (dir ? Dp_b : Dp_f)[d];
  __syncthreads();

  if (fast) {
    for (int t = 0; t < CL; ++t) {
      long r = r0 + t;
      float dt = b2f(dp[r * 1024 + d]);
      float u  = b2f(up[r * 1024 + d]);
      float du = dt * u;
      float Ep[16];
      EP_FAST(dt, Ep);
      float y = 0.f;
#pragma unroll
      for (int s = 0; s < D_STATE; ++s) {
        h[s] = fmaf(h[s], Ep[s], du * bc[t][s]);
        y = fmaf(h[s], bc[t][16 + s], y);
      }
      float zs = b2f(zp[r * 1024 + d]);
      float yv = fmaf(u, Dd, y);
      yp[r * 1024 + d] = f2b(yv * zs);
    }
  } else {
    for (int t = 0; t < CL; ++t) {
      long r = r0 + t;
      float dt = b2f(dp[r * 1024 + d]);
      float u  = b2f(up[r * 1024 + d]);
      float du = dt * u;
      float y = 0.f;
#pragma unroll
      for (int s = 0; s < D_STATE; ++s) {
        h[s] = fmaf(h[s], __expf(dt * Ar[s]), du * bc[t][s]);
        y = fmaf(h[s], bc[t][16 + s], y);
      }
      float zs = b2f(zp[r * 1024 + d]);
      float yv = fmaf(u, Dd, y);
      yp[r * 1024 + d] = f2b(yv * zs);
    }
  }
}

extern "C" void kernel_launch(void* const* d_in, const int* in_sizes, int n_in,
                              void* d_out, int out_size, void* d_ws, size_t ws_size,
                              hipStream_t stream)
{
  const float* x = (const float*)d_in[0];
  float* out = (float*)d_out;
  char* ws = (char*)d_ws;
  ushort* zsilu  = (ushort*)(ws);                     // 32 MiB
  ushort* ucv    = (ushort*)(ws + (32ul << 20));      // 32 MiB (=ydz)
  ushort* u_bf   = (ushort*)(ws + (64ul << 20));      // 32 MiB (=delta)
  ushort* hend   = (ushort*)(ws + (96ul << 20));      // 32 MiB
  float*  dtsum  = (float*)(ws + (128ul << 20));      //  4 MiB
  ushort* dblb   = (ushort*)(ws + (132ul << 20));     //  2 MiB
  ushort* out_wb = (ushort*)(ws + (134ul << 20));     //  2 MiB
  ushort* xbf    = hend;                              // transient in hend slab
  ushort* in_wb  = hend + (8ul << 19);
  ushort* xp_wb  = hend + (12ul << 19);
  ushort* dt_wb  = xp_wb + 131072;
  ushort* delta  = u_bf;
  ushort* ydz    = ucv;

  ConvArgs ca;
  int bcur = 0, si = 0;
  auto addseg = [&](const float* s, ushort* d, int nelem) {
    ca.seg[si].s = (const float4*)s; ca.seg[si].d = (ushort4*)d;
    ca.seg[si].n4 = nelem / 4; ca.seg[si].bstart = bcur;
    bcur += (nelem / 4 + 255) / 256; ++si;
  };
  addseg(x, xbf, NROWS * D_MODEL);
  addseg((const float*)d_in[1], in_wb, 2048 * 512);
  addseg((const float*)d_in[10], in_wb + 2048 * 512, 2048 * 512);
  addseg((const float*)d_in[9], out_wb, 512 * 1024);
  addseg((const float*)d_in[18], out_wb + 512 * 1024, 512 * 1024);
  addseg((const float*)d_in[4], xp_wb, 64 * 1024);
  addseg((const float*)d_in[13], xp_wb + 65536, 64 * 1024);
  addseg((const float*)d_in[5], dt_wb, 1024 * 32);
  addseg((const float*)d_in[14], dt_wb + 32768, 1024 * 32);

  dim3 blk(256);
  convert_all<<<dim3(bcur), blk, 0, stream>>>(ca);

  // 1) merged in_proj: 256x128 tiles, 2 blocks/CU
  inproj256<<<dim3(4096 / 128, NROWS / 256), dim3(512), 0, stream>>>(
      xbf, D_MODEL, in_wb, D_MODEL, u_bf, zsilu, D_MODEL);
  // 2) conv + silu, both dirs
  conv_silu<<<dim3(2 * NROWS), blk, 0, stream>>>(
      u_bf, (const float*)d_in[2], (const float*)d_in[11],
      (const float*)d_in[3], (const float*)d_in[12], ucv);
  // 3) x_proj, both dirs block-diag
  gemm_bf16<64, 64, 2, 2, 4, 0, 1><<<dim3(1, 256), blk, 0, stream>>>(
      ucv, D_INNER, nullptr, xp_wb, D_INNER, nullptr,
      nullptr, dblb, nullptr, 64, D_INNER, nullptr, nullptr, 65536, 0, 0);
  // 4) dt_proj + softplus, both dirs block-diag (vectorized epilogue)
  gemm_bf16<128, 128, 2, 2, 1, 0, 1><<<dim3(8, 128), blk, 0, stream>>>(
      dblb, 64, nullptr, dt_wb, DT_RANK, nullptr,
      nullptr, delta, nullptr, D_INNER, DT_RANK,
      (const float*)d_in[6], (const float*)d_in[15], 32768, 0, 0);
  // 5) chunked scan, both dirs
  const float* Alf = (const float*)d_in[7];
  const float* Alb = (const float*)d_in[16];
  scan_partA<<<dim3(2 * BATCH * CH * 1024 / 256), blk, 0, stream>>>(
      delta, ucv, dblb, Alf, Alb, hend, dtsum);
  scan_partB<<<dim3(2 * BATCH * 16 * 1024 / 256), blk, 0, stream>>>(
      hend, dtsum, Alf, Alb);
  scan_partC<<<dim3(2 * BATCH * CH * 1024 / 256), blk, 0, stream>>>(
      delta, ucv, dblb, Alf, Alb,
      (const float*)d_in[8], (const float*)d_in[17], zsilu, hend, ydz);
  // 6) out_proj, both dirs in one K=2048 dispatch
  gemm_bf16<128, 128, 2, 2, 0, 1, 0><<<dim3(4, 64), blk, 0, stream>>>(
      ydz, D_INNER, ydz + USLAB, out_wb, D_INNER, out_wb + 512 * 1024,
      out, nullptr, nullptr, D_MODEL, 2 * D_INNER, nullptr, nullptr, 0, 0, 0);
}

// Round 18
// 235.651 us; speedup vs baseline: 1.3056x; 1.0492x over previous
//
#include <hip/hip_runtime.h>
#include <math.h>

#define BATCH 8
#define SEQ 1024
#define D_MODEL 512
#define D_INNER 1024
#define D_STATE 16
#define DT_RANK 32
#define NROWS (BATCH * SEQ)   // 8192
#define CH 64                 // chunks per sequence
#define CL 16                 // chunk length
#define USLAB 8388608l        // 8192*1024 elems (one dir slab)

typedef short short8 __attribute__((ext_vector_type(8)));
typedef float f32x4 __attribute__((ext_vector_type(4)));

__device__ __forceinline__ float sigmoidf_(float x) { return 1.f / (1.f + __expf(-x)); }

__device__ __forceinline__ float softplus_(float v) {
  return (v > 20.f) ? v : __logf(1.f + __expf(v));
}

__device__ __forceinline__ ushort f2b(float f) {  // fp32 -> bf16 RNE
  uint u = __float_as_uint(f);
  return (ushort)((u + 0x7FFFu + ((u >> 16) & 1u)) >> 16);
}
__device__ __forceinline__ float b2f(ushort u) {
  return __uint_as_float(((uint)u) << 16);
}

__device__ __forceinline__ void gload16(const ushort* g, const ushort* l) {
  __builtin_amdgcn_global_load_lds(
      (const __attribute__((address_space(1))) void*)g,
      (__attribute__((address_space(3))) void*)l, 16, 0, 0);
}

__device__ __forceinline__ int revrow(int m) {
  return (m & ~1023) | (1023 - (m & 1023));
}

#define VMCNT0 asm volatile("s_waitcnt vmcnt(0)" ::: "memory")
#define VMCNT2 asm volatile("s_waitcnt vmcnt(2)" ::: "memory")
#define VMCNT3 asm volatile("s_waitcnt vmcnt(3)" ::: "memory")
#define VMCNT4 asm volatile("s_waitcnt vmcnt(4)" ::: "memory")

// ========== in_proj: 256x128 tile, 8 waves, counted-vmcnt, 2 blocks/CU =====
__global__ __launch_bounds__(512, 4) void inproj256(
    const ushort* __restrict__ A, int lda,      // [8192][512]
    const ushort* __restrict__ B, int ldb,      // [4096][512]
    ushort* __restrict__ Cu, ushort* __restrict__ Cz,
    int K)
{
  __shared__ ushort As[3][256 * 32];            // 48 KB
  __shared__ ushort Bs[3][128 * 32];            // 24 KB
  const int tid = threadIdx.x;
  const int w = tid >> 6, lane = tid & 63;

  const int nwg = gridDim.x * gridDim.y;        // 1024, %8 == 0
  int bid = blockIdx.y * gridDim.x + blockIdx.x;
  int wgid = (bid & 7) * (nwg >> 3) + (bid >> 3);
  const int bm = (wgid / gridDim.x) * 256;
  const int bn = (wgid % gridDim.x) * 128;

  const int wr = w >> 1, wc = w & 1;            // 4x2 wave grid
  const int rw0 = wr * 64, cw0 = wc * 64;
  const int srow = w * 16 + (lane >> 2);
  const int scol = (((lane & 3) ^ ((lane >> 3) & 3)) << 3);
  const int rchunk = (((lane >> 4) ^ (((lane & 15) >> 1) & 3)) << 3);

  f32x4 acc[4][4] = {};

  auto stage = [&](int buf, int k0) {
#pragma unroll
    for (int half = 0; half < 2; ++half) {
      int gm = bm + half * 128 + srow;
      gload16(A + (long)gm * lda + k0 + scol, &As[buf][(half * 128 + w * 16) * 32]);
    }
    int gn = bn + srow;
    gload16(B + (long)gn * ldb + k0 + scol, &Bs[buf][(w * 16) * 32]);
  };

  const int NT = K >> 5;
  stage(0, 0);
  stage(1, 32);
  VMCNT3;
  __builtin_amdgcn_s_barrier();

  int buf = 0;
  for (int t = 0; t < NT; ++t) {
    short8 a[4], b[4];
#pragma unroll
    for (int i = 0; i < 4; ++i)
      a[i] = *(const short8*)&As[buf][(rw0 + i * 16 + (lane & 15)) * 32 + rchunk];
#pragma unroll
    for (int j = 0; j < 4; ++j)
      b[j] = *(const short8*)&Bs[buf][(cw0 + j * 16 + (lane & 15)) * 32 + rchunk];
    int sbuf = (buf >= 1) ? buf - 1 : buf + 2;
    if (t + 2 < NT) {
      stage(sbuf, (t + 2) << 5);
      VMCNT3;
    } else if (t + 1 < NT) {
      VMCNT0;
    }
    __builtin_amdgcn_s_barrier();
    __builtin_amdgcn_s_setprio(1);
#pragma unroll
    for (int i = 0; i < 4; ++i)
#pragma unroll
      for (int j = 0; j < 4; ++j)
        acc[i][j] = __builtin_amdgcn_mfma_f32_16x16x32_bf16(a[i], b[j], acc[i][j], 0, 0, 0);
    __builtin_amdgcn_s_setprio(0);
    buf = (buf == 2) ? 0 : buf + 1;
  }
  __builtin_amdgcn_s_barrier();

  const int bdir = bn >> 11;
  const int bz = ((bn & 2047) >= 1024);
  const int bncol = bn & 1023;
  ushort* Cp = (bz ? Cz : Cu) + (long)bdir * USLAB;
  ushort* scr = &As[0][0] + w * 1024;

#pragma unroll
  for (int i = 0; i < 4; ++i) {
#pragma unroll
    for (int r = 0; r < 4; ++r)
#pragma unroll
      for (int j = 0; j < 4; ++j) {
        float v = acc[i][j][r];
        if (bz) v = v * sigmoidf_(v);
        scr[((lane >> 4) * 4 + r) * 64 + j * 16 + (lane & 15)] = f2b(v);
      }
#pragma unroll
    for (int q = 0; q < 2; ++q) {
      int r16 = (lane >> 3) + q * 8;
      short8 pk = *(const short8*)&scr[r16 * 64 + (lane & 7) * 8];
      int m = bm + rw0 + i * 16 + r16;
      int row = bdir ? revrow(m) : m;
      *(short8*)&Cp[(long)row * 1024 + bncol + cw0 + (lane & 7) * 8] = pk;
    }
  }
}

// -------- bf16 MFMA GEMM: 3-buffer counted-vmcnt, single barrier/K-tile ----
// EPI: 0 = fp32 store (revC/accumC), 1 = softplus->bf16 (LDS-transposed),
//      4 = plain bf16
template<int BM, int BN, int RW, int CW, int EPI, int DUALK, int MDIAG>
__global__ __launch_bounds__(256) void gemm_bf16(
    const ushort* __restrict__ A, int lda, const ushort* __restrict__ A2,
    const ushort* __restrict__ B, int ldb, const ushort* __restrict__ B2,
    float* __restrict__ Cf, ushort* __restrict__ Cb,
    int ldc, int K, const float* __restrict__ bias, const float* __restrict__ bias2,
    int b_stride, int revC, int accumC)
{
  constexpr int MI = BM / RW / 16;
  constexpr int NJ = BN / CW / 16;
  constexpr int LPS = BM / 64 + BN / 64;   // loads per stage per thread
  __shared__ ushort As[3][BM * 32];
  __shared__ ushort Bs[3][BN * 32];
  const int tid = threadIdx.x;
  const int w = tid >> 6, lane = tid & 63;

  const int nwg = gridDim.x * gridDim.y;
  int bid = blockIdx.y * gridDim.x + blockIdx.x;
  int wgid = (bid & 7) * (nwg >> 3) + (bid >> 3);
  const int bm = (wgid / gridDim.x) * BM;
  const int bn = (wgid % gridDim.x) * BN;

  if (MDIAG) {
    int mdir = (bm >= NROWS) ? 1 : 0;
    B += mdir * b_stride;
    if (mdir) bias = bias2;
  }

  const int rw0 = (w / CW) * (MI * 16);
  const int cw0 = (w % CW) * (NJ * 16);
  const int srow = w * 16 + (lane >> 2);
  const int scol = (((lane & 3) ^ ((lane >> 3) & 3)) << 3);
  const int rchunk = (((lane >> 4) ^ (((lane & 15) >> 1) & 3)) << 3);

  f32x4 acc[MI][NJ] = {};

  auto stage = [&](int buf, int k0) {
    const ushort* Ap = A;
    const ushort* Bp = B;
    int kc = k0;
    bool hi = false;
    if (DUALK && k0 >= (K >> 1)) { Ap = A2; Bp = B2; kc = k0 - (K >> 1); hi = true; }
#pragma unroll
    for (int it = 0; it < BM / 64; ++it) {
      int gm = bm + it * 64 + srow;
      int arow = (DUALK && hi) ? revrow(gm) : gm;
      gload16(Ap + (long)arow * lda + kc + scol, &As[buf][(it * 64 + w * 16) * 32]);
    }
#pragma unroll
    for (int it = 0; it < BN / 64; ++it) {
      int gn = bn + it * 64 + srow;
      gload16(Bp + (long)gn * ldb + kc + scol, &Bs[buf][(it * 64 + w * 16) * 32]);
    }
  };

  const int NT = K >> 5;
  stage(0, 0);
  if (NT > 1) {
    stage(1, 32);
    if constexpr (LPS == 2) VMCNT2; else VMCNT4;
  } else {
    VMCNT0;
  }
  __builtin_amdgcn_s_barrier();

  int buf = 0;
  for (int t = 0; t < NT; ++t) {
    short8 a[MI], b[NJ];
#pragma unroll
    for (int i = 0; i < MI; ++i)
      a[i] = *(const short8*)&As[buf][(rw0 + i * 16 + (lane & 15)) * 32 + rchunk];
#pragma unroll
    for (int j = 0; j < NJ; ++j)
      b[j] = *(const short8*)&Bs[buf][(cw0 + j * 16 + (lane & 15)) * 32 + rchunk];
    int sbuf = (buf >= 1) ? buf - 1 : buf + 2;
    if (t + 2 < NT) {
      stage(sbuf, (t + 2) << 5);
      if constexpr (LPS == 2) VMCNT2; else VMCNT4;
    } else if (t + 1 < NT) {
      VMCNT0;
    }
    __builtin_amdgcn_s_barrier();
    __builtin_amdgcn_s_setprio(1);
#pragma unroll
    for (int i = 0; i < MI; ++i)
#pragma unroll
      for (int j = 0; j < NJ; ++j)
        acc[i][j] = __builtin_amdgcn_mfma_f32_16x16x32_bf16(a[i], b[j], acc[i][j], 0, 0, 0);
    __builtin_amdgcn_s_setprio(0);
    buf = (buf == 2) ? 0 : buf + 1;
  }
  __builtin_amdgcn_s_barrier();

  if (EPI == 1) {
    ushort* scr = &As[0][0] + w * 1024;
#pragma unroll
    for (int i = 0; i < MI; ++i) {
#pragma unroll
      for (int r = 0; r < 4; ++r)
#pragma unroll
        for (int j = 0; j < NJ; ++j) {
          int n = bn + cw0 + j * 16 + (lane & 15);
          float v = softplus_(acc[i][j][r] + bias[n]);
          scr[((lane >> 4) * 4 + r) * 64 + j * 16 + (lane & 15)] = f2b(v);
        }
#pragma unroll
      for (int q = 0; q < 2; ++q) {
        int r16 = (lane >> 3) + q * 8;
        short8 pk = *(const short8*)&scr[r16 * 64 + (lane & 7) * 8];
        int m = bm + rw0 + i * 16 + r16;
        *(short8*)&Cb[(long)m * ldc + bn + cw0 + (lane & 7) * 8] = pk;
      }
    }
  } else {
#pragma unroll
    for (int i = 0; i < MI; ++i)
#pragma unroll
      for (int r = 0; r < 4; ++r) {
        int m = bm + rw0 + i * 16 + (lane >> 4) * 4 + r;
        int crow = revC ? revrow(m) : m;
#pragma unroll
        for (int j = 0; j < NJ; ++j) {
          int n = bn + cw0 + j * 16 + (lane & 15);
          float v = acc[i][j][r];
          if (EPI == 0) {
            float* p = Cf + (long)crow * ldc + n;
            if (accumC) *p += v; else *p = v;
          } else {  // EPI == 4
            Cb[(long)crow * ldc + n] = f2b(v);
          }
        }
      }
  }
}

// ---------------- fused fp32->bf16 converter (x + 8 weight tensors) --------
struct Seg { const float4* s; ushort4* d; int n4; int bstart; };
struct ConvArgs { Seg seg[9]; };

__global__ __launch_bounds__(256) void convert_all(ConvArgs a)
{
  int blk = blockIdx.x;
  int i = 0;
#pragma unroll
  for (int k = 1; k < 9; ++k) if (blk >= a.seg[k].bstart) i = k;
  int idx = (blk - a.seg[i].bstart) * 256 + threadIdx.x;
  if (idx >= a.seg[i].n4) return;
  float4 v = a.seg[i].s[idx];
  ushort4 o;
  o.x = f2b(v.x); o.y = f2b(v.y); o.z = f2b(v.z); o.w = f2b(v.w);
  a.seg[i].d[idx] = o;
}

// ------------- conv1d(k=4) + bias + silu, both dirs (4 d/thread) -----------
__global__ __launch_bounds__(256) void conv_silu(
    const ushort* __restrict__ u_bf,
    const float* __restrict__ cw_f, const float* __restrict__ cw_b,
    const float* __restrict__ cb_f, const float* __restrict__ cb_b,
    ushort* __restrict__ uc_bf)
{
  long i = (long)blockIdx.x * 256 + threadIdx.x;
  int dir = (int)(i >> 21);
  int r = (int)(i >> 8) & 8191;
  int d0 = ((int)i & 255) << 2;
  int t = r & (SEQ - 1);
  const float* cw = dir ? cw_b : cw_f;
  const float* cb = dir ? cb_b : cb_f;
  const ushort* p = u_bf + dir * USLAB + (long)r * D_INNER + d0;
  ushort4 u0 = *(const ushort4*)p;
  ushort4 u1 = (t >= 1) ? *(const ushort4*)(p - 1024) : ushort4{0, 0, 0, 0};
  ushort4 u2 = (t >= 2) ? *(const ushort4*)(p - 2048) : ushort4{0, 0, 0, 0};
  ushort4 u3 = (t >= 3) ? *(const ushort4*)(p - 3072) : ushort4{0, 0, 0, 0};
  float4 bb = *(const float4*)(cb + d0);
  float ub0[4] = {b2f(u0.x), b2f(u0.y), b2f(u0.z), b2f(u0.w)};
  float ub1[4] = {b2f(u1.x), b2f(u1.y), b2f(u1.z), b2f(u1.w)};
  float ub2[4] = {b2f(u2.x), b2f(u2.y), b2f(u2.z), b2f(u2.w)};
  float ub3[4] = {b2f(u3.x), b2f(u3.y), b2f(u3.z), b2f(u3.w)};
  float bbv[4] = {bb.x, bb.y, bb.z, bb.w};
  ushort ov[4];
#pragma unroll
  for (int j = 0; j < 4; ++j) {
    float4 wj = *(const float4*)(cw + (d0 + j) * 4);
    float acc = bbv[j];
    acc = fmaf(wj.w, ub0[j], acc);
    acc = fmaf(wj.z, ub1[j], acc);
    acc = fmaf(wj.y, ub2[j], acc);
    acc = fmaf(wj.x, ub3[j], acc);
    ov[j] = f2b(acc * sigmoidf_(acc));
  }
  ushort4 o;
  o.x = ov[0]; o.y = ov[1]; o.z = ov[2]; o.w = ov[3];
  *(ushort4*)(uc_bf + dir * USLAB + (long)r * D_INNER + d0) = o;
}

// Decay powers E^(s+1), s=0..15, from E = exp(-dt).
#define EP_FAST(dt, Ep)                                        \
  {                                                            \
    float E1 = __expf(-(dt));                                  \
    float E2 = E1 * E1, E4 = E2 * E2, E8 = E4 * E4;            \
    Ep[0] = E1;  Ep[1] = E2;      Ep[2] = E2 * E1;             \
    Ep[3] = E4;  Ep[4] = E4 * E1; Ep[5] = E4 * E2;             \
    Ep[6] = E4 * Ep[2]; Ep[7] = E8;  Ep[8] = E8 * E1;          \
    Ep[9] = E8 * E2; Ep[10] = E8 * Ep[2]; Ep[11] = E8 * E4;    \
    Ep[12] = E8 * Ep[4]; Ep[13] = E8 * Ep[5];                  \
    Ep[14] = E8 * Ep[6]; Ep[15] = E8 * E8;                     \
  }

__device__ __forceinline__ bool a_is_arange(const float* Ar) {
  bool ok = true;
#pragma unroll
  for (int s = 0; s < D_STATE; ++s)
    ok = ok && (fabsf(Ar[s] + (float)(s + 1)) <= 1e-3f * (float)(s + 1));
  return ok;
}

// ---------------- chunked selective scan (both dirs in one grid) -----------
__global__ __launch_bounds__(256) void scan_partA(
    const ushort* __restrict__ delta_bf,
    const ushort* __restrict__ ucv_bf,
    const ushort* __restrict__ dblb,
    const float* __restrict__ A_log_f, const float* __restrict__ A_log_b,
    ushort* __restrict__ hend,
    float* __restrict__ dtsum_buf)
{
  __shared__ float bc[CL][16];
  long idx = (long)blockIdx.x * 256 + threadIdx.x;
  int d = (int)idx & 1023;
  int c = ((int)idx >> 10) & (CH - 1);
  int b = ((int)idx >> 16) & 7;
  int dir = (int)(idx >> 19);
  const long r0 = (long)b * SEQ + c * CL;
  const ushort* dblp = dblb + (long)dir * NROWS * 64;
  {
    int tt = threadIdx.x >> 4, ss = threadIdx.x & 15;
    bc[tt][ss] = b2f(dblp[(r0 + tt) * 64 + 32 + ss]);
  }
  const float* Alog = dir ? A_log_b : A_log_f;
  const ushort* dp = delta_bf + dir * USLAB;
  const ushort* up = ucv_bf + dir * USLAB;
  float Ar[D_STATE];
#pragma unroll
  for (int s = 0; s < D_STATE; ++s) Ar[s] = -__expf(Alog[d * D_STATE + s]);
  const bool fast = a_is_arange(Ar);
  float h[D_STATE] = {0.f};
  float dtsum = 0.f;
  __syncthreads();

  if (fast) {
    for (int t = 0; t < CL; ++t) {
      long r = r0 + t;
      float dt = b2f(dp[r * 1024 + d]);
      float u  = b2f(up[r * 1024 + d]);
      float du = dt * u;
      dtsum += dt;
      float Ep[16];
      EP_FAST(dt, Ep);
#pragma unroll
      for (int s = 0; s < D_STATE; ++s)
        h[s] = fmaf(h[s], Ep[s], du * bc[t][s]);
    }
  } else {
    for (int t = 0; t < CL; ++t) {
      long r = r0 + t;
      float dt = b2f(dp[r * 1024 + d]);
      float u  = b2f(up[r * 1024 + d]);
      float du = dt * u;
      dtsum += dt;
#pragma unroll
      for (int s = 0; s < D_STATE; ++s)
        h[s] = fmaf(h[s], __expf(dt * Ar[s]), du * bc[t][s]);
    }
  }
  long base = ((long)((dir * 8 + b) * CH + c) * D_STATE) * 1024 + d;
#pragma unroll
  for (int s = 0; s < D_STATE; ++s) hend[base + s * 1024] = f2b(h[s]);
  dtsum_buf[(long)((dir * 8 + b) * CH + c) * 1024 + d] = dtsum;
}

__global__ __launch_bounds__(256) void scan_partB(
    ushort* __restrict__ hend,
    const float* __restrict__ dtsum_buf,
    const float* __restrict__ A_log_f, const float* __restrict__ A_log_b)
{
  long idx = (long)blockIdx.x * 256 + threadIdx.x;
  int d = (int)idx & 1023;
  int s = ((int)idx >> 10) & 15;
  int b = ((int)idx >> 14) & 7;
  int dir = (int)(idx >> 17);
  const float* Alog = dir ? A_log_b : A_log_f;
  float Ars = -__expf(Alog[d * D_STATE + s]);
  float H = 0.f;
  for (int c = 0; c < CH; ++c) {
    long off = ((long)((dir * 8 + b) * CH + c) * D_STATE + s) * 1024 + d;
    float he = b2f(hend[off]);
    float P = __expf(Ars * dtsum_buf[(long)((dir * 8 + b) * CH + c) * 1024 + d]);
    hend[off] = f2b(H);
    H = fmaf(P, H, he);
  }
}

__global__ __launch_bounds__(256) void scan_partC(
    const ushort* __restrict__ delta_bf,
    const ushort* __restrict__ ucv_bf,
    const ushort* __restrict__ dblb,
    const float* __restrict__ A_log_f, const float* __restrict__ A_log_b,
    const float* __restrict__ Dp_f, const float* __restrict__ Dp_b,
    const ushort* __restrict__ zsilu_bf,
    const ushort* __restrict__ hinit,
    ushort* __restrict__ ydz_bf)
{
  __shared__ float bc[CL][32];
  long idx = (long)blockIdx.x * 256 + threadIdx.x;
  int d = (int)idx & 1023;
  int c = ((int)idx >> 10) & (CH - 1);
  int b = ((int)idx >> 16) & 7;
  int dir = (int)(idx >> 19);
  const long r0 = (long)b * SEQ + c * CL;
  const ushort* dblp = dblb + (long)dir * NROWS * 64;
  {
    int tt = threadIdx.x >> 4, cc = (threadIdx.x & 15) * 2;
    ushort2 v = *(const ushort2*)&dblp[(r0 + tt) * 64 + 32 + cc];
    bc[tt][cc] = b2f(v.x); bc[tt][cc + 1] = b2f(v.y);
  }
  const float* Alog = dir ? A_log_b : A_log_f;
  const ushort* dp = delta_bf + dir * USLAB;
  const ushort* up = ucv_bf + dir * USLAB;
  const ushort* zp = zsilu_bf + dir * USLAB;
  ushort* yp = ydz_bf + dir * USLAB;
  float Ar[D_STATE];
#pragma unroll
  for (int s = 0; s < D_STATE; ++s) Ar[s] = -__expf(Alog[d * D_STATE + s]);
  const bool fast = a_is_arange(Ar);
  float h[D_STATE];
  long base = ((long)((dir * 8 + b) * CH + c) * D_STATE) * 1024 + d;
#pragma unroll
  for (int s = 0; s < D_STATE; ++s) h[s] = b2f(hinit[base + s * 1024]);
  float Dd = (dir ? Dp_b : Dp_f)[d];
  __syncthreads();

  if (fast) {
    for (int t = 0; t < CL; ++t) {
      long r = r0 + t;
      float dt = b2f(dp[r * 1024 + d]);
      float u  = b2f(up[r * 1024 + d]);
      float du = dt * u;
      float Ep[16];
      EP_FAST(dt, Ep);
      float y = 0.f;
#pragma unroll
      for (int s = 0; s < D_STATE; ++s) {
        h[s] = fmaf(h[s], Ep[s], du * bc[t][s]);
        y = fmaf(h[s], bc[t][16 + s], y);
      }
      float zs = b2f(zp[r * 1024 + d]);
      float yv = fmaf(u, Dd, y);
      yp[r * 1024 + d] = f2b(yv * zs);
    }
  } else {
    for (int t = 0; t < CL; ++t) {
      long r = r0 + t;
      float dt = b2f(dp[r * 1024 + d]);
      float u  = b2f(up[r * 1024 + d]);
      float du = dt * u;
      float y = 0.f;
#pragma unroll
      for (int s = 0; s < D_STATE; ++s) {
        h[s] = fmaf(h[s], __expf(dt * Ar[s]), du * bc[t][s]);
        y = fmaf(h[s], bc[t][16 + s], y);
      }
      float zs = b2f(zp[r * 1024 + d]);
      float yv = fmaf(u, Dd, y);
      yp[r * 1024 + d] = f2b(yv * zs);
    }
  }
}

extern "C" void kernel_launch(void* const* d_in, const int* in_sizes, int n_in,
                              void* d_out, int out_size, void* d_ws, size_t ws_size,
                              hipStream_t stream)
{
  const float* x = (const float*)d_in[0];
  float* out = (float*)d_out;
  char* ws = (char*)d_ws;
  ushort* zsilu  = (ushort*)(ws);                     // 32 MiB
  ushort* ucv    = (ushort*)(ws + (32ul << 20));      // 32 MiB (=ydz)
  ushort* u_bf   = (ushort*)(ws + (64ul << 20));      // 32 MiB (=delta)
  ushort* hend   = (ushort*)(ws + (96ul << 20));      // 32 MiB
  float*  dtsum  = (float*)(ws + (128ul << 20));      //  4 MiB
  ushort* dblb   = (ushort*)(ws + (132ul << 20));     //  2 MiB
  ushort* out_wb = (ushort*)(ws + (134ul << 20));     //  2 MiB
  ushort* xbf    = hend;                              // transient in hend slab
  ushort* in_wb  = hend + (8ul << 19);
  ushort* xp_wb  = hend + (12ul << 19);
  ushort* dt_wb  = xp_wb + 131072;
  ushort* delta  = u_bf;
  ushort* ydz    = ucv;

  ConvArgs ca;
  int bcur = 0, si = 0;
  auto addseg = [&](const float* s, ushort* d, int nelem) {
    ca.seg[si].s = (const float4*)s; ca.seg[si].d = (ushort4*)d;
    ca.seg[si].n4 = nelem / 4; ca.seg[si].bstart = bcur;
    bcur += (nelem / 4 + 255) / 256; ++si;
  };
  addseg(x, xbf, NROWS * D_MODEL);
  addseg((const float*)d_in[1], in_wb, 2048 * 512);
  addseg((const float*)d_in[10], in_wb + 2048 * 512, 2048 * 512);
  addseg((const float*)d_in[9], out_wb, 512 * 1024);
  addseg((const float*)d_in[18], out_wb + 512 * 1024, 512 * 1024);
  addseg((const float*)d_in[4], xp_wb, 64 * 1024);
  addseg((const float*)d_in[13], xp_wb + 65536, 64 * 1024);
  addseg((const float*)d_in[5], dt_wb, 1024 * 32);
  addseg((const float*)d_in[14], dt_wb + 32768, 1024 * 32);

  dim3 blk(256);
  convert_all<<<dim3(bcur), blk, 0, stream>>>(ca);

  // 1) merged in_proj: 256x128 tiles, 2 blocks/CU
  inproj256<<<dim3(4096 / 128, NROWS / 256), dim3(512), 0, stream>>>(
      xbf, D_MODEL, in_wb, D_MODEL, u_bf, zsilu, D_MODEL);
  // 2) conv + silu, both dirs
  conv_silu<<<dim3(2 * NROWS), blk, 0, stream>>>(
      u_bf, (const float*)d_in[2], (const float*)d_in[11],
      (const float*)d_in[3], (const float*)d_in[12], ucv);
  // 3) x_proj, both dirs block-diag
  gemm_bf16<64, 64, 2, 2, 4, 0, 1><<<dim3(1, 256), blk, 0, stream>>>(
      ucv, D_INNER, nullptr, xp_wb, D_INNER, nullptr,
      nullptr, dblb, 64, D_INNER, nullptr, nullptr, 65536, 0, 0);
  // 4) dt_proj + softplus, both dirs block-diag (vectorized epilogue)
  gemm_bf16<128, 128, 2, 2, 1, 0, 1><<<dim3(8, 128), blk, 0, stream>>>(
      dblb, 64, nullptr, dt_wb, DT_RANK, nullptr,
      nullptr, delta, D_INNER, DT_RANK,
      (const float*)d_in[6], (const float*)d_in[15], 32768, 0, 0);
  // 5) chunked scan, both dirs
  const float* Alf = (const float*)d_in[7];
  const float* Alb = (const float*)d_in[16];
  scan_partA<<<dim3(2 * BATCH * CH * 1024 / 256), blk, 0, stream>>>(
      delta, ucv, dblb, Alf, Alb, hend, dtsum);
  scan_partB<<<dim3(2 * BATCH * 16 * 1024 / 256), blk, 0, stream>>>(
      hend, dtsum, Alf, Alb);
  scan_partC<<<dim3(2 * BATCH * CH * 1024 / 256), blk, 0, stream>>>(
      delta, ucv, dblb, Alf, Alb,
      (const float*)d_in[8], (const float*)d_in[17], zsilu, hend, ydz);
  // 6) out_proj, both dirs in one K=2048 dispatch
  gemm_bf16<128, 128, 2, 2, 0, 1, 0><<<dim3(4, 64), blk, 0, stream>>>(
      ydz, D_INNER, ydz + USLAB, out_wb, D_INNER, out_wb + 512 * 1024,
      out, nullptr, D_MODEL, 2 * D_INNER, nullptr, nullptr, 0, 0, 0);
}